// Round 1
// baseline (13466.556 us; speedup 1.0000x reference)
//
#include <hip/hip_runtime.h>

#define WIDTH 256
#define HW 65536
#define IMG 16777216   // 4*64*HW
#define NIMG 256

__device__ __forceinline__ float lrelu_f(float v){ return v > 0.f ? v : 0.01f*v; }

// ---------------- proj conv: 3 -> 64, 3x3, pad 1 ----------------
__global__ __launch_bounds__(256) void k_conv_proj(const float* __restrict__ x,
    const float* __restrict__ w, const float* __restrict__ bias, float* __restrict__ out)
{
    __shared__ float wl[27][64];          // [c*9+pos][o]
    const int tid = threadIdx.x;
    const int og = tid >> 6, xg = tid & 63;
    const int o0 = og * 16, x0 = xg * 4;
    const int b = blockIdx.x >> 8, y = blockIdx.x & 255;

    for (int idx = tid; idx < 27 * 64; idx += 256) {
        const int o = idx & 63, cp = idx >> 6;
        wl[cp][o] = w[o * 27 + cp];
    }
    __syncthreads();

    float acc[16][4];
#pragma unroll
    for (int i = 0; i < 16; i++) { acc[i][0]=0.f; acc[i][1]=0.f; acc[i][2]=0.f; acc[i][3]=0.f; }

#pragma unroll
    for (int c = 0; c < 3; c++) {
        const float* src = x + ((size_t)b * 3 + c) * HW;
#pragma unroll
        for (int dy = 0; dy < 3; dy++) {
            const int yy = y + dy - 1;
            float vv[6];
            if (yy >= 0 && yy < 256) {
                const float* r = src + (size_t)yy * WIDTH;
                vv[0] = (x0 > 0) ? r[x0 - 1] : 0.f;
                const float4 m = *(const float4*)(r + x0);
                vv[1] = m.x; vv[2] = m.y; vv[3] = m.z; vv[4] = m.w;
                vv[5] = (x0 < 252) ? r[x0 + 4] : 0.f;
            } else { vv[0]=vv[1]=vv[2]=vv[3]=vv[4]=vv[5]=0.f; }
#pragma unroll
            for (int dx = 0; dx < 3; dx++) {
#pragma unroll
                for (int oi = 0; oi < 16; oi++) {
                    const float wv = wl[c * 9 + dy * 3 + dx][o0 + oi];
                    acc[oi][0] += wv * vv[dx + 0];
                    acc[oi][1] += wv * vv[dx + 1];
                    acc[oi][2] += wv * vv[dx + 2];
                    acc[oi][3] += wv * vv[dx + 3];
                }
            }
        }
    }
#pragma unroll
    for (int oi = 0; oi < 16; oi++) {
        const int o = o0 + oi;
        const float bv = bias[o];
        float4 r;
        r.x = acc[oi][0] + bv; r.y = acc[oi][1] + bv; r.z = acc[oi][2] + bv; r.w = acc[oi][3] + bv;
        const size_t off = ((size_t)(b * 64 + o)) * HW + (size_t)y * WIDTH + x0;
        *(float4*)(out + off) = r;
    }
}

// ---------------- per-image stats: mean + inv_std ----------------
__global__ __launch_bounds__(256) void k_stats(const float* __restrict__ src, float* __restrict__ st)
{
    const float* p = src + (size_t)blockIdx.x * HW;
    float s = 0.f, s2 = 0.f;
    for (int i = threadIdx.x; i < HW / 4; i += 256) {
        const float4 v = ((const float4*)p)[i];
        s  += v.x + v.y + v.z + v.w;
        s2 += v.x * v.x + v.y * v.y + v.z * v.z + v.w * v.w;
    }
#pragma unroll
    for (int off = 32; off > 0; off >>= 1) {
        s  += __shfl_down(s, off, 64);
        s2 += __shfl_down(s2, off, 64);
    }
    __shared__ float ls[4], ls2[4];
    const int wid = threadIdx.x >> 6, lane = threadIdx.x & 63;
    if (lane == 0) { ls[wid] = s; ls2[wid] = s2; }
    __syncthreads();
    if (threadIdx.x == 0) {
        float S = 0.f, S2 = 0.f;
#pragma unroll
        for (int w = 0; w < 4; w++) { S += ls[w]; S2 += ls2[w]; }
        const float m = S / 65536.f;
        const float var = S2 / 65536.f - m * m;
        st[blockIdx.x * 2]     = m;
        st[blockIdx.x * 2 + 1] = rsqrtf(var + 1e-5f);
    }
}

// ---------------- attention MLP (single block) ----------------
__global__ __launch_bounds__(256) void k_attention(const float* __restrict__ st0,
    const float* __restrict__ wa1, const float* __restrict__ wa2, float* __restrict__ a2o)
{
    __shared__ float a1s[64];
    const int tid = threadIdx.x;
    if (tid < 64) {
        const int b = tid >> 4, o = tid & 15;
        float s = 0.f;
        for (int c = 0; c < 64; c++) s += wa1[o * 64 + c] * st0[(b * 64 + c) * 2];
        a1s[b * 16 + o] = lrelu_f(s);
    }
    __syncthreads();
    {
        const int b = tid >> 6, c = tid & 63;
        float s = 0.f;
#pragma unroll
        for (int o = 0; o < 16; o++) s += wa2[c * 16 + o] * a1s[b * 16 + o];
        a2o[tid] = 1.f / (1.f + expf(-s));
    }
}

// ---------------- depthwise 3x3 with folded attention scale ----------------
__global__ __launch_bounds__(256) void k_dw(const float* __restrict__ xp, const float* __restrict__ a2,
    const float* __restrict__ wref, const float* __restrict__ bref, float* __restrict__ out)
{
    const int tid = threadIdx.x;
    const int img = blockIdx.x >> 8, y = blockIdx.x & 255;
    const int c = img & 63;
    const float* src = xp + (size_t)img * HW;
    float wv[9];
#pragma unroll
    for (int k = 0; k < 9; k++) wv[k] = wref[c * 9 + k];
    const float scale = a2[img], bb = bref[c];
    const int xx = tid;
    float s = 0.f;
#pragma unroll
    for (int dy = 0; dy < 3; dy++) {
        const int yy = y + dy - 1;
        if (yy < 0 || yy > 255) continue;
        const float* r = src + (size_t)yy * WIDTH;
#pragma unroll
        for (int dx = 0; dx < 3; dx++) {
            const int xc_ = xx + dx - 1;
            if (xc_ < 0 || xc_ > 255) continue;
            s += wv[dy * 3 + dx] * r[xc_];
        }
    }
    out[(size_t)img * HW + (size_t)y * WIDTH + xx] = bb + scale * s;
}

// ---------------- in-place instance-norm + leaky relu ----------------
__global__ __launch_bounds__(256) void k_norm(float* __restrict__ buf, const float* __restrict__ st)
{
    const size_t i = (size_t)blockIdx.x * 256 + threadIdx.x;   // float4 index
    const int img = (int)(i >> 14);                            // 16384 float4 per image
    const float m = st[img * 2], s = st[img * 2 + 1];
    float4 v = ((float4*)buf)[i];
    v.x = lrelu_f((v.x - m) * s);
    v.y = lrelu_f((v.y - m) * s);
    v.z = lrelu_f((v.z - m) * s);
    v.w = lrelu_f((v.w - m) * s);
    ((float4*)buf)[i] = v;
}

// ---------------- Dirichlet kernel tables ----------------
__global__ void k_tables(float* __restrict__ kr2, float* __restrict__ ki2)
{
    const int t = blockIdx.x * 256 + threadIdx.x;
    if (t < 512) {
        const int tm = t & 255;
        const double PI = 3.14159265358979323846;
        const double th = 2.0 * PI * (double)tm / 256.0;
        double sr = 1.0;
        for (int k = 1; k <= 37; k++) sr += 2.0 * cos((double)k * th);
        sr += cos(38.0 * th);
        kr2[t] = (float)(sr / 256.0);
        ki2[t] = (float)(-sin(38.0 * th) / 256.0);
    }
}

// ---------------- DFT stage 1: A+iB = K (circ-conv over y) applied to xp ----------------
__global__ __launch_bounds__(256) void k_dft1(const float* __restrict__ xp,
    const float* __restrict__ kr2, const float* __restrict__ ki2,
    float* __restrict__ A, float* __restrict__ Bm)
{
    __shared__ float X[32][256];
    const int tid = threadIdx.x;
    const int img = blockIdx.x >> 3, strip = blockIdx.x & 7;
    const int yg = tid >> 6, xg = tid & 63;
    const int y0 = strip * 32 + yg * 8, x0 = xg * 4;
    const float* src = xp + (size_t)img * HW;

    float aR[8][4], aI[8][4];
#pragma unroll
    for (int j = 0; j < 8; j++)
#pragma unroll
        for (int i = 0; i < 4; i++) { aR[j][i] = 0.f; aI[j][i] = 0.f; }

    for (int ch = 0; ch < 8; ch++) {
        __syncthreads();
#pragma unroll
        for (int k = 0; k < 8; k++) {
            const int f4 = k * 256 + tid;
            const int row = f4 >> 6, col = (f4 & 63) * 4;
            *(float4*)&X[row][col] = *(const float4*)(src + (size_t)(ch * 32 + row) * WIDTH + col);
        }
        __syncthreads();
        for (int yl = 0; yl < 32; yl++) {
            const int yp = ch * 32 + yl;
            const int base = __builtin_amdgcn_readfirstlane(y0 - yp + 256);
            const float4 xv = *(const float4*)&X[yl][x0];
#pragma unroll
            for (int j = 0; j < 8; j++) {
                const float wr = kr2[base + j];
                const float wi = ki2[base + j];
                aR[j][0] += wr * xv.x; aR[j][1] += wr * xv.y; aR[j][2] += wr * xv.z; aR[j][3] += wr * xv.w;
                aI[j][0] += wi * xv.x; aI[j][1] += wi * xv.y; aI[j][2] += wi * xv.z; aI[j][3] += wi * xv.w;
            }
        }
    }
#pragma unroll
    for (int j = 0; j < 8; j++) {
        const size_t off = (size_t)img * HW + (size_t)(y0 + j) * WIDTH + x0;
        *(float4*)(A  + off) = make_float4(aR[j][0], aR[j][1], aR[j][2], aR[j][3]);
        *(float4*)(Bm + off) = make_float4(aI[j][0], aI[j][1], aI[j][2], aI[j][3]);
    }
}

// ---------------- DFT stage 2: low = Re(K circ-conv over x of (A+iB)) ----------------
__global__ __launch_bounds__(256) void k_dft2(const float* __restrict__ A,
    const float* __restrict__ Bm, const float* __restrict__ kr2, const float* __restrict__ ki2,
    float* __restrict__ low)
{
    __shared__ float tR[512], tI[512];
    const int tid = threadIdx.x;
    for (int t = tid; t < 512; t += 256) { tR[t] = kr2[t]; tI[t] = ki2[t]; }
    __syncthreads();
    const int img = blockIdx.x >> 3, strip = blockIdx.x & 7;
    const int yg = tid >> 6, xg = tid & 63;
    const int y0 = strip * 32 + yg * 8;
    const float* Ab = A  + (size_t)img * HW;
    const float* Bb = Bm + (size_t)img * HW;

    float acc[8][4];
#pragma unroll
    for (int j = 0; j < 8; j++)
#pragma unroll
        for (int i = 0; i < 4; i++) acc[j][i] = 0.f;

    for (int xq = 0; xq < 256; xq++) {
        const int rbase = __builtin_amdgcn_readfirstlane(y0 * WIDTH + xq);
        float av[8], bv[8];
#pragma unroll
        for (int j = 0; j < 8; j++) { av[j] = Ab[rbase + j * WIDTH]; bv[j] = Bb[rbase + j * WIDTH]; }
#pragma unroll
        for (int i = 0; i < 4; i++) {
            const int x = xg + 64 * i;
            const float wr = tR[x - xq + 256];
            const float wi = tI[x - xq + 256];
#pragma unroll
            for (int j = 0; j < 8; j++) acc[j][i] += wr * av[j] - wi * bv[j];
        }
    }
#pragma unroll
    for (int j = 0; j < 8; j++)
#pragma unroll
        for (int i = 0; i < 4; i++)
            low[(size_t)img * HW + (size_t)(y0 + j) * WIDTH + xg + 64 * i] = acc[j][i];
}

// ---------------- W_eff = collapse(grouped 3x3, 1x1) ----------------
__global__ __launch_bounds__(256) void k_weff(const float* __restrict__ w_u1,
    const float* __restrict__ w_con, float* __restrict__ weff)
{
    const int idx = blockIdx.x * 256 + threadIdx.x;   // 64*128*9 = 73728
    if (idx >= 64 * 128 * 9) return;
    const int pos = idx % 9;
    const int g = (idx / 9) & 127;
    const int o = idx / 1152;
    float s = 0.f;
#pragma unroll
    for (int j = 0; j < 4; j++) s += w_u1[o * 512 + g * 4 + j] * w_con[(g * 4 + j) * 9 + pos];
    weff[idx] = s;
}

// ---------------- generic conv: CIN -> 64, KS in {1,3}, optional residual add ----------------
template<int CIN, int KS, bool ADD>
__global__ __launch_bounds__(256) void k_conv(const float* __restrict__ in0,
    const float* __restrict__ in1, const float* __restrict__ wt,
    const float* __restrict__ bias, const float* __restrict__ addsrc,
    float* __restrict__ out)
{
    __shared__ float wl[8][KS * KS][64];
    const int tid = threadIdx.x;
    const int og = tid >> 6, xg = tid & 63;
    const int o0 = og * 16, x0 = xg * 4;
    const int b = blockIdx.x >> 8, y = blockIdx.x & 255;

    float acc[16][4];
#pragma unroll
    for (int i = 0; i < 16; i++) { acc[i][0]=0.f; acc[i][1]=0.f; acc[i][2]=0.f; acc[i][3]=0.f; }

    for (int c0 = 0; c0 < CIN; c0 += 8) {
        __syncthreads();
        for (int idx = tid; idx < 8 * KS * KS * 64; idx += 256) {
            const int o = idx & 63;
            const int rest = idx >> 6;
            const int pos = rest % (KS * KS);
            const int cc = rest / (KS * KS);
            wl[cc][pos][o] = wt[(size_t)(o * CIN + c0 + cc) * (KS * KS) + pos];
        }
        __syncthreads();
#pragma unroll
        for (int cc = 0; cc < 8; cc++) {
            const int c = c0 + cc;
            const float* src = (CIN == 128 && c >= 64)
                ? (in1 + ((size_t)(b * 64 + (c - 64))) * HW)
                : (in0 + ((size_t)(b * 64 + c)) * HW);
            if constexpr (KS == 3) {
#pragma unroll
                for (int dy = 0; dy < 3; dy++) {
                    const int yy = y + dy - 1;
                    float vv[6];
                    if (yy >= 0 && yy < 256) {
                        const float* r = src + (size_t)yy * WIDTH;
                        vv[0] = (x0 > 0) ? r[x0 - 1] : 0.f;
                        const float4 m = *(const float4*)(r + x0);
                        vv[1] = m.x; vv[2] = m.y; vv[3] = m.z; vv[4] = m.w;
                        vv[5] = (x0 < 252) ? r[x0 + 4] : 0.f;
                    } else { vv[0]=vv[1]=vv[2]=vv[3]=vv[4]=vv[5]=0.f; }
#pragma unroll
                    for (int dx = 0; dx < 3; dx++) {
#pragma unroll
                        for (int oi = 0; oi < 16; oi++) {
                            const float wv = wl[cc][dy * 3 + dx][o0 + oi];
                            acc[oi][0] += wv * vv[dx + 0];
                            acc[oi][1] += wv * vv[dx + 1];
                            acc[oi][2] += wv * vv[dx + 2];
                            acc[oi][3] += wv * vv[dx + 3];
                        }
                    }
                }
            } else {
                const float4 m = *(const float4*)(src + (size_t)y * WIDTH + x0);
#pragma unroll
                for (int oi = 0; oi < 16; oi++) {
                    const float wv = wl[cc][0][o0 + oi];
                    acc[oi][0] += wv * m.x; acc[oi][1] += wv * m.y;
                    acc[oi][2] += wv * m.z; acc[oi][3] += wv * m.w;
                }
            }
        }
    }
#pragma unroll
    for (int oi = 0; oi < 16; oi++) {
        const int o = o0 + oi;
        const float bv = bias[o];
        float4 r;
        r.x = acc[oi][0] + bv; r.y = acc[oi][1] + bv; r.z = acc[oi][2] + bv; r.w = acc[oi][3] + bv;
        const size_t off = ((size_t)(b * 64 + o)) * HW + (size_t)y * WIDTH + x0;
        if (ADD) {
            const float4 ad = *(const float4*)(addsrc + off);
            r.x += ad.x; r.y += ad.y; r.z += ad.z; r.w += ad.w;
        }
        *(float4*)(out + off) = r;
    }
}

// ---------------- 2x2 max pool ----------------
__global__ __launch_bounds__(256) void k_maxpool(const float* __restrict__ feat, float* __restrict__ out)
{
    const int idx = blockIdx.x * 256 + threadIdx.x;      // 4*64*128*128
    const int xo = idx & 127;
    const int yo = (idx >> 7) & 127;
    const int img = idx >> 14;
    const float* p = feat + (size_t)img * HW + (size_t)(yo * 2) * WIDTH + xo * 2;
    out[idx] = fmaxf(fmaxf(p[0], p[1]), fmaxf(p[WIDTH], p[WIDTH + 1]));
}

extern "C" void kernel_launch(void* const* d_in, const int* in_sizes, int n_in,
                              void* d_out, int out_size, void* d_ws, size_t ws_size,
                              hipStream_t stream)
{
    const float* x      = (const float*)d_in[0];
    const float* w_proj = (const float*)d_in[1];
    const float* b_proj = (const float*)d_in[2];
    const float* w_a1   = (const float*)d_in[3];
    const float* w_a2   = (const float*)d_in[4];
    const float* w_ref  = (const float*)d_in[5];
    const float* b_ref  = (const float*)d_in[6];
    const float* w_fuse = (const float*)d_in[7];
    const float* b_fuse = (const float*)d_in[8];
    const float* w_con  = (const float*)d_in[9];
    const float* w_u1   = (const float*)d_in[10];
    const float* b_u1   = (const float*)d_in[11];
    const float* w_u2   = (const float*)d_in[12];
    const float* b_u2   = (const float*)d_in[13];
    const float* w_sc   = (const float*)d_in[14];
    const float* b_sc   = (const float*)d_in[15];

    float* wsf  = (float*)d_ws;
    float* buf0 = wsf;                       // xp -> low -> u2raw/u_b
    float* buf1 = wsf + (size_t)IMG;         // xw (normalized in place)
    float* buf2 = wsf + (size_t)2 * IMG;     // A -> low_f (normalized in place)
    float* aux  = wsf + (size_t)3 * IMG;
    float* st0  = aux;                       // 512 each (mean, inv_std interleaved)
    float* st1  = aux + 512;
    float* st2  = aux + 1024;
    float* st3  = aux + 1536;
    float* st4  = aux + 2048;
    float* a2b  = aux + 2560;                // 256
    float* kr2  = aux + 2816;                // 512
    float* ki2  = aux + 3328;                // 512
    float* weff = aux + 3840;                // 73728

    float* fout = (float*)d_out;             // B -> u1raw/u_a -> feat
    float* pout = fout + (size_t)IMG;        // pooled

    k_tables<<<2, 256, 0, stream>>>(kr2, ki2);
    k_conv_proj<<<1024, 256, 0, stream>>>(x, w_proj, b_proj, buf0);
    k_stats<<<NIMG, 256, 0, stream>>>(buf0, st0);
    k_attention<<<1, 256, 0, stream>>>(st0, w_a1, w_a2, a2b);
    k_dw<<<65536, 256, 0, stream>>>(buf0, a2b, w_ref, b_ref, buf1);
    k_stats<<<NIMG, 256, 0, stream>>>(buf1, st1);
    k_norm<<<16384, 256, 0, stream>>>(buf1, st1);
    k_dft1<<<2048, 256, 0, stream>>>(buf0, kr2, ki2, buf2, fout);
    k_dft2<<<2048, 256, 0, stream>>>(buf2, fout, kr2, ki2, buf0);
    k_conv<64, 1, false><<<1024, 256, 0, stream>>>(buf0, buf0, w_fuse, b_fuse, nullptr, buf2);
    k_stats<<<NIMG, 256, 0, stream>>>(buf2, st2);
    k_norm<<<16384, 256, 0, stream>>>(buf2, st2);
    k_weff<<<288, 256, 0, stream>>>(w_u1, w_con, weff);
    k_conv<128, 3, false><<<1024, 256, 0, stream>>>(buf1, buf2, weff, b_u1, nullptr, fout);
    k_stats<<<NIMG, 256, 0, stream>>>(fout, st3);
    k_norm<<<16384, 256, 0, stream>>>(fout, st3);
    k_conv<64, 3, false><<<1024, 256, 0, stream>>>(fout, fout, w_u2, b_u2, nullptr, buf0);
    k_stats<<<NIMG, 256, 0, stream>>>(buf0, st4);
    k_norm<<<16384, 256, 0, stream>>>(buf0, st4);
    k_conv<128, 1, true><<<1024, 256, 0, stream>>>(buf1, buf2, w_sc, b_sc, buf0, fout);
    k_maxpool<<<16384, 256, 0, stream>>>(fout, pout);
}

// Round 2
// 4021.932 us; speedup vs baseline: 3.3483x; 3.3483x over previous
//
#include <hip/hip_runtime.h>

#define WIDTH 256
#define HW 65536
#define IMG 16777216   // 4*64*HW
#define NIMG 256

__device__ __forceinline__ float lrelu_f(float v){ return v > 0.f ? v : 0.01f*v; }

// ---------------- per-image stats: mean + inv_std ----------------
__global__ __launch_bounds__(256) void k_stats(const float* __restrict__ src, float* __restrict__ st)
{
    const float* p = src + (size_t)blockIdx.x * HW;
    float s = 0.f, s2 = 0.f;
    for (int i = threadIdx.x; i < HW / 4; i += 256) {
        const float4 v = ((const float4*)p)[i];
        s  += v.x + v.y + v.z + v.w;
        s2 += v.x * v.x + v.y * v.y + v.z * v.z + v.w * v.w;
    }
#pragma unroll
    for (int off = 32; off > 0; off >>= 1) {
        s  += __shfl_down(s, off, 64);
        s2 += __shfl_down(s2, off, 64);
    }
    __shared__ float ls[4], ls2[4];
    const int wid = threadIdx.x >> 6, lane = threadIdx.x & 63;
    if (lane == 0) { ls[wid] = s; ls2[wid] = s2; }
    __syncthreads();
    if (threadIdx.x == 0) {
        float S = 0.f, S2 = 0.f;
#pragma unroll
        for (int w = 0; w < 4; w++) { S += ls[w]; S2 += ls2[w]; }
        const float m = S / 65536.f;
        const float var = S2 / 65536.f - m * m;
        st[blockIdx.x * 2]     = m;
        st[blockIdx.x * 2 + 1] = rsqrtf(var + 1e-5f);
    }
}

// ---------------- attention MLP (single block) ----------------
__global__ __launch_bounds__(256) void k_attention(const float* __restrict__ st0,
    const float* __restrict__ wa1, const float* __restrict__ wa2, float* __restrict__ a2o)
{
    __shared__ float a1s[64];
    const int tid = threadIdx.x;
    if (tid < 64) {
        const int b = tid >> 4, o = tid & 15;
        float s = 0.f;
        for (int c = 0; c < 64; c++) s += wa1[o * 64 + c] * st0[(b * 64 + c) * 2];
        a1s[b * 16 + o] = lrelu_f(s);
    }
    __syncthreads();
    {
        const int b = tid >> 6, c = tid & 63;
        float s = 0.f;
#pragma unroll
        for (int o = 0; o < 16; o++) s += wa2[c * 16 + o] * a1s[b * 16 + o];
        a2o[tid] = 1.f / (1.f + expf(-s));
    }
}

// ---------------- depthwise 3x3 with folded attention scale ----------------
__global__ __launch_bounds__(256) void k_dw(const float* __restrict__ xp, const float* __restrict__ a2,
    const float* __restrict__ wref, const float* __restrict__ bref, float* __restrict__ out)
{
    const int tid = threadIdx.x;
    const int img = blockIdx.x >> 8, y = blockIdx.x & 255;
    const int c = img & 63;
    const float* src = xp + (size_t)img * HW;
    float wv[9];
#pragma unroll
    for (int k = 0; k < 9; k++) wv[k] = wref[c * 9 + k];
    const float scale = a2[img], bb = bref[c];
    const int xx = tid;
    float s = 0.f;
#pragma unroll
    for (int dy = 0; dy < 3; dy++) {
        const int yy = y + dy - 1;
        if (yy < 0 || yy > 255) continue;
        const float* r = src + (size_t)yy * WIDTH;
#pragma unroll
        for (int dx = 0; dx < 3; dx++) {
            const int xc_ = xx + dx - 1;
            if (xc_ < 0 || xc_ > 255) continue;
            s += wv[dy * 3 + dx] * r[xc_];
        }
    }
    out[(size_t)img * HW + (size_t)y * WIDTH + xx] = bb + scale * s;
}

// ---------------- in-place instance-norm + leaky relu ----------------
__global__ __launch_bounds__(256) void k_norm(float* __restrict__ buf, const float* __restrict__ st)
{
    const size_t i = (size_t)blockIdx.x * 256 + threadIdx.x;   // float4 index
    const int img = (int)(i >> 14);                            // 16384 float4 per image
    const float m = st[img * 2], s = st[img * 2 + 1];
    float4 v = ((float4*)buf)[i];
    v.x = lrelu_f((v.x - m) * s);
    v.y = lrelu_f((v.y - m) * s);
    v.z = lrelu_f((v.z - m) * s);
    v.w = lrelu_f((v.w - m) * s);
    ((float4*)buf)[i] = v;
}

// ---------------- Dirichlet kernel tables ----------------
__global__ void k_tables(float* __restrict__ kr2, float* __restrict__ ki2)
{
    const int t = blockIdx.x * 256 + threadIdx.x;
    if (t < 512) {
        const int tm = t & 255;
        const double PI = 3.14159265358979323846;
        const double th = 2.0 * PI * (double)tm / 256.0;
        double sr = 1.0;
        for (int k = 1; k <= 37; k++) sr += 2.0 * cos((double)k * th);
        sr += cos(38.0 * th);
        kr2[t] = (float)(sr / 256.0);
        ki2[t] = (float)(-sin(38.0 * th) / 256.0);
    }
}

// ---------------- DFT stage 1: A+iB = K (circ-conv over y) applied to xp ----------------
__global__ __launch_bounds__(256) void k_dft1(const float* __restrict__ xp,
    const float* __restrict__ kr2, const float* __restrict__ ki2,
    float* __restrict__ A, float* __restrict__ Bm)
{
    __shared__ float X[32][256];
    const int tid = threadIdx.x;
    const int img = blockIdx.x >> 3, strip = blockIdx.x & 7;
    const int yg = tid >> 6, xg = tid & 63;
    const int y0 = strip * 32 + yg * 8, x0 = xg * 4;
    const float* src = xp + (size_t)img * HW;

    float aR[8][4], aI[8][4];
#pragma unroll
    for (int j = 0; j < 8; j++)
#pragma unroll
        for (int i = 0; i < 4; i++) { aR[j][i] = 0.f; aI[j][i] = 0.f; }

    for (int ch = 0; ch < 8; ch++) {
        __syncthreads();
#pragma unroll
        for (int k = 0; k < 8; k++) {
            const int f4 = k * 256 + tid;
            const int row = f4 >> 6, col = (f4 & 63) * 4;
            *(float4*)&X[row][col] = *(const float4*)(src + (size_t)(ch * 32 + row) * WIDTH + col);
        }
        __syncthreads();
        for (int yl = 0; yl < 32; yl++) {
            const int yp = ch * 32 + yl;
            const int base = __builtin_amdgcn_readfirstlane(y0 - yp + 256);
            const float4 xv = *(const float4*)&X[yl][x0];
#pragma unroll
            for (int j = 0; j < 8; j++) {
                const float wr = kr2[base + j];
                const float wi = ki2[base + j];
                aR[j][0] += wr * xv.x; aR[j][1] += wr * xv.y; aR[j][2] += wr * xv.z; aR[j][3] += wr * xv.w;
                aI[j][0] += wi * xv.x; aI[j][1] += wi * xv.y; aI[j][2] += wi * xv.z; aI[j][3] += wi * xv.w;
            }
        }
    }
#pragma unroll
    for (int j = 0; j < 8; j++) {
        const size_t off = (size_t)img * HW + (size_t)(y0 + j) * WIDTH + x0;
        *(float4*)(A  + off) = make_float4(aR[j][0], aR[j][1], aR[j][2], aR[j][3]);
        *(float4*)(Bm + off) = make_float4(aI[j][0], aI[j][1], aI[j][2], aI[j][3]);
    }
}

// ---------------- DFT stage 2: low = Re(K circ-conv over x of (A+iB)) ----------------
__global__ __launch_bounds__(256) void k_dft2(const float* __restrict__ A,
    const float* __restrict__ Bm, const float* __restrict__ kr2, const float* __restrict__ ki2,
    float* __restrict__ low)
{
    __shared__ float tR[512], tI[512];
    const int tid = threadIdx.x;
    for (int t = tid; t < 512; t += 256) { tR[t] = kr2[t]; tI[t] = ki2[t]; }
    __syncthreads();
    const int img = blockIdx.x >> 3, strip = blockIdx.x & 7;
    const int yg = tid >> 6, xg = tid & 63;
    const int y0 = strip * 32 + yg * 8;
    const float* Ab = A  + (size_t)img * HW;
    const float* Bb = Bm + (size_t)img * HW;

    float acc[8][4];
#pragma unroll
    for (int j = 0; j < 8; j++)
#pragma unroll
        for (int i = 0; i < 4; i++) acc[j][i] = 0.f;

    for (int xq = 0; xq < 256; xq++) {
        const int rbase = __builtin_amdgcn_readfirstlane(y0 * WIDTH + xq);
        float av[8], bv[8];
#pragma unroll
        for (int j = 0; j < 8; j++) { av[j] = Ab[rbase + j * WIDTH]; bv[j] = Bb[rbase + j * WIDTH]; }
#pragma unroll
        for (int i = 0; i < 4; i++) {
            const int x = xg + 64 * i;
            const float wr = tR[x - xq + 256];
            const float wi = tI[x - xq + 256];
#pragma unroll
            for (int j = 0; j < 8; j++) acc[j][i] += wr * av[j] - wi * bv[j];
        }
    }
#pragma unroll
    for (int j = 0; j < 8; j++)
#pragma unroll
        for (int i = 0; i < 4; i++)
            low[(size_t)img * HW + (size_t)(y0 + j) * WIDTH + xg + 64 * i] = acc[j][i];
}

// ---------------- W_eff = collapse(grouped 3x3, 1x1) ----------------
__global__ __launch_bounds__(256) void k_weff(const float* __restrict__ w_u1,
    const float* __restrict__ w_con, float* __restrict__ weff)
{
    const int idx = blockIdx.x * 256 + threadIdx.x;   // 64*128*9 = 73728
    if (idx >= 64 * 128 * 9) return;
    const int pos = idx % 9;
    const int g = (idx / 9) & 127;
    const int o = idx / 1152;
    float s = 0.f;
#pragma unroll
    for (int j = 0; j < 4; j++) s += w_u1[o * 512 + g * 4 + j] * w_con[(g * 4 + j) * 9 + pos];
    weff[idx] = s;
}

// ---------------- generic conv: CIN -> 64, KS in {1,3}, optional residual add ----------------
// Block: one (b, y) row x 32 output channels. Threads: 8 o-groups (4 out each) x
// 32 x-groups (8 px each) -> 32 accumulators/thread (no spills; R1 had 64 acc ->
// VGPR=256 cap + 22 GB scratch traffic). Weights in LDS with o innermost: each
// thread's 4 weights = one broadcast ds_read_b128 per 32 FMAs.
template<int CIN, int CHUNK, int KS, bool ADD>
__global__ __launch_bounds__(256) void k_conv(const float* __restrict__ in0,
    const float* __restrict__ in1, const float* __restrict__ wt,
    const float* __restrict__ bias, const float* __restrict__ addsrc,
    float* __restrict__ out)
{
    __shared__ float wl[CHUNK][KS * KS][32];
    const int tid = threadIdx.x;
    const int og = tid >> 5, xg = tid & 31;
    const int half = blockIdx.x & 1;
    const int y = (blockIdx.x >> 1) & 255;
    const int b = blockIdx.x >> 9;
    const int o_base = half * 32;
    const int o0l = og * 4;            // local output within the 32-wide half
    const int x0 = xg * 8;
    constexpr int IC0 = (CIN == 128) ? 64 : CIN;   // channels held by in0 per batch

    float acc[4][8];
#pragma unroll
    for (int i = 0; i < 4; i++)
#pragma unroll
        for (int j = 0; j < 8; j++) acc[i][j] = 0.f;

    for (int c0 = 0; c0 < CIN; c0 += CHUNK) {
        __syncthreads();
        for (int idx = tid; idx < CHUNK * KS * KS * 32; idx += 256) {
            const int o = idx & 31;
            const int rest = idx >> 5;
            const int pos = rest % (KS * KS);
            const int cc = rest / (KS * KS);
            wl[cc][pos][o] = wt[((size_t)(o_base + o) * CIN + c0 + cc) * (KS * KS) + pos];
        }
        __syncthreads();
#pragma unroll
        for (int cc = 0; cc < CHUNK; cc++) {
            const int c = c0 + cc;
            const float* src = (CIN == 128 && c >= 64)
                ? (in1 + ((size_t)(b * 64 + (c - 64))) * HW)
                : (in0 + ((size_t)b * IC0 + c) * HW);
            if constexpr (KS == 3) {
#pragma unroll
                for (int dy = 0; dy < 3; dy++) {
                    const int yy = y + dy - 1;
                    float vv[10];
                    if (yy >= 0 && yy < 256) {
                        const float* r = src + (size_t)yy * WIDTH;
                        vv[0] = (x0 > 0) ? r[x0 - 1] : 0.f;
                        const float4 m0 = *(const float4*)(r + x0);
                        const float4 m1 = *(const float4*)(r + x0 + 4);
                        vv[1] = m0.x; vv[2] = m0.y; vv[3] = m0.z; vv[4] = m0.w;
                        vv[5] = m1.x; vv[6] = m1.y; vv[7] = m1.z; vv[8] = m1.w;
                        vv[9] = (x0 < 248) ? r[x0 + 8] : 0.f;
                    } else {
#pragma unroll
                        for (int q = 0; q < 10; q++) vv[q] = 0.f;
                    }
#pragma unroll
                    for (int dx = 0; dx < 3; dx++) {
                        const float4 w4 = *(const float4*)&wl[cc][dy * 3 + dx][o0l];
                        const float wv[4] = { w4.x, w4.y, w4.z, w4.w };
#pragma unroll
                        for (int oi = 0; oi < 4; oi++)
#pragma unroll
                            for (int px = 0; px < 8; px++)
                                acc[oi][px] += wv[oi] * vv[px + dx];
                    }
                }
            } else {
                const float4 m0 = *(const float4*)(src + (size_t)y * WIDTH + x0);
                const float4 m1 = *(const float4*)(src + (size_t)y * WIDTH + x0 + 4);
                const float vv[8] = { m0.x, m0.y, m0.z, m0.w, m1.x, m1.y, m1.z, m1.w };
                const float4 w4 = *(const float4*)&wl[cc][0][o0l];
                const float wv[4] = { w4.x, w4.y, w4.z, w4.w };
#pragma unroll
                for (int oi = 0; oi < 4; oi++)
#pragma unroll
                    for (int px = 0; px < 8; px++)
                        acc[oi][px] += wv[oi] * vv[px];
            }
        }
    }
#pragma unroll
    for (int oi = 0; oi < 4; oi++) {
        const int o = o_base + o0l + oi;
        const float bv = bias[o];
        const size_t off = ((size_t)(b * 64 + o)) * HW + (size_t)y * WIDTH + x0;
        float4 r0, r1;
        r0.x = acc[oi][0] + bv; r0.y = acc[oi][1] + bv; r0.z = acc[oi][2] + bv; r0.w = acc[oi][3] + bv;
        r1.x = acc[oi][4] + bv; r1.y = acc[oi][5] + bv; r1.z = acc[oi][6] + bv; r1.w = acc[oi][7] + bv;
        if constexpr (ADD) {
            const float4 a0 = *(const float4*)(addsrc + off);
            const float4 a1 = *(const float4*)(addsrc + off + 4);
            r0.x += a0.x; r0.y += a0.y; r0.z += a0.z; r0.w += a0.w;
            r1.x += a1.x; r1.y += a1.y; r1.z += a1.z; r1.w += a1.w;
        }
        *(float4*)(out + off) = r0;
        *(float4*)(out + off + 4) = r1;
    }
}

// ---------------- 2x2 max pool ----------------
__global__ __launch_bounds__(256) void k_maxpool(const float* __restrict__ feat, float* __restrict__ out)
{
    const int idx = blockIdx.x * 256 + threadIdx.x;      // 4*64*128*128
    const int xo = idx & 127;
    const int yo = (idx >> 7) & 127;
    const int img = idx >> 14;
    const float* p = feat + (size_t)img * HW + (size_t)(yo * 2) * WIDTH + xo * 2;
    out[idx] = fmaxf(fmaxf(p[0], p[1]), fmaxf(p[WIDTH], p[WIDTH + 1]));
}

extern "C" void kernel_launch(void* const* d_in, const int* in_sizes, int n_in,
                              void* d_out, int out_size, void* d_ws, size_t ws_size,
                              hipStream_t stream)
{
    const float* x      = (const float*)d_in[0];
    const float* w_proj = (const float*)d_in[1];
    const float* b_proj = (const float*)d_in[2];
    const float* w_a1   = (const float*)d_in[3];
    const float* w_a2   = (const float*)d_in[4];
    const float* w_ref  = (const float*)d_in[5];
    const float* b_ref  = (const float*)d_in[6];
    const float* w_fuse = (const float*)d_in[7];
    const float* b_fuse = (const float*)d_in[8];
    const float* w_con  = (const float*)d_in[9];
    const float* w_u1   = (const float*)d_in[10];
    const float* b_u1   = (const float*)d_in[11];
    const float* w_u2   = (const float*)d_in[12];
    const float* b_u2   = (const float*)d_in[13];
    const float* w_sc   = (const float*)d_in[14];
    const float* b_sc   = (const float*)d_in[15];

    float* wsf  = (float*)d_ws;
    float* buf0 = wsf;                       // xp -> low -> u2raw/u_b
    float* buf1 = wsf + (size_t)IMG;         // xw (normalized in place)
    float* buf2 = wsf + (size_t)2 * IMG;     // A -> low_f (normalized in place)
    float* aux  = wsf + (size_t)3 * IMG;
    float* st0  = aux;                       // 512 each (mean, inv_std interleaved)
    float* st1  = aux + 512;
    float* st2  = aux + 1024;
    float* st3  = aux + 1536;
    float* st4  = aux + 2048;
    float* a2b  = aux + 2560;                // 256
    float* kr2  = aux + 2816;                // 512
    float* ki2  = aux + 3328;                // 512
    float* weff = aux + 3840;                // 73728

    float* fout = (float*)d_out;             // B -> u1raw/u_a -> feat
    float* pout = fout + (size_t)IMG;        // pooled

    k_tables<<<2, 256, 0, stream>>>(kr2, ki2);
    k_conv<3, 3, 3, false><<<2048, 256, 0, stream>>>(x, nullptr, w_proj, b_proj, nullptr, buf0);
    k_stats<<<NIMG, 256, 0, stream>>>(buf0, st0);
    k_attention<<<1, 256, 0, stream>>>(st0, w_a1, w_a2, a2b);
    k_dw<<<65536, 256, 0, stream>>>(buf0, a2b, w_ref, b_ref, buf1);
    k_stats<<<NIMG, 256, 0, stream>>>(buf1, st1);
    k_norm<<<16384, 256, 0, stream>>>(buf1, st1);
    k_dft1<<<2048, 256, 0, stream>>>(buf0, kr2, ki2, buf2, fout);
    k_dft2<<<2048, 256, 0, stream>>>(buf2, fout, kr2, ki2, buf0);
    k_conv<64, 8, 1, false><<<2048, 256, 0, stream>>>(buf0, nullptr, w_fuse, b_fuse, nullptr, buf2);
    k_stats<<<NIMG, 256, 0, stream>>>(buf2, st2);
    k_norm<<<16384, 256, 0, stream>>>(buf2, st2);
    k_weff<<<288, 256, 0, stream>>>(w_u1, w_con, weff);
    k_conv<128, 8, 3, false><<<2048, 256, 0, stream>>>(buf1, buf2, weff, b_u1, nullptr, fout);
    k_stats<<<NIMG, 256, 0, stream>>>(fout, st3);
    k_norm<<<16384, 256, 0, stream>>>(fout, st3);
    k_conv<64, 8, 3, false><<<2048, 256, 0, stream>>>(fout, nullptr, w_u2, b_u2, nullptr, buf0);
    k_stats<<<NIMG, 256, 0, stream>>>(buf0, st4);
    k_norm<<<16384, 256, 0, stream>>>(buf0, st4);
    k_conv<128, 8, 1, true><<<2048, 256, 0, stream>>>(buf1, buf2, w_sc, b_sc, buf0, fout);
    k_maxpool<<<16384, 256, 0, stream>>>(fout, pout);
}

// Round 3
// 3107.432 us; speedup vs baseline: 4.3337x; 1.2943x over previous
//
#include <hip/hip_runtime.h>

#define WIDTH 256
#define HW 65536
#define IMG 16777216   // 4*64*HW
#define NIMG 256

__device__ __forceinline__ float lrelu_f(float v){ return v > 0.f ? v : 0.01f*v; }

// ---------------- per-image stats: mean + inv_std ----------------
__global__ __launch_bounds__(256) void k_stats(const float* __restrict__ src, float* __restrict__ st)
{
    const float* p = src + (size_t)blockIdx.x * HW;
    float s = 0.f, s2 = 0.f;
    for (int i = threadIdx.x; i < HW / 4; i += 256) {
        const float4 v = ((const float4*)p)[i];
        s  += v.x + v.y + v.z + v.w;
        s2 += v.x * v.x + v.y * v.y + v.z * v.z + v.w * v.w;
    }
#pragma unroll
    for (int off = 32; off > 0; off >>= 1) {
        s  += __shfl_down(s, off, 64);
        s2 += __shfl_down(s2, off, 64);
    }
    __shared__ float ls[4], ls2[4];
    const int wid = threadIdx.x >> 6, lane = threadIdx.x & 63;
    if (lane == 0) { ls[wid] = s; ls2[wid] = s2; }
    __syncthreads();
    if (threadIdx.x == 0) {
        float S = 0.f, S2 = 0.f;
#pragma unroll
        for (int w = 0; w < 4; w++) { S += ls[w]; S2 += ls2[w]; }
        const float m = S / 65536.f;
        const float var = S2 / 65536.f - m * m;
        st[blockIdx.x * 2]     = m;
        st[blockIdx.x * 2 + 1] = rsqrtf(var + 1e-5f);
    }
}

// ---------------- attention MLP (single block) ----------------
__global__ __launch_bounds__(256) void k_attention(const float* __restrict__ st0,
    const float* __restrict__ wa1, const float* __restrict__ wa2, float* __restrict__ a2o)
{
    __shared__ float a1s[64];
    const int tid = threadIdx.x;
    if (tid < 64) {
        const int b = tid >> 4, o = tid & 15;
        float s = 0.f;
        for (int c = 0; c < 64; c++) s += wa1[o * 64 + c] * st0[(b * 64 + c) * 2];
        a1s[b * 16 + o] = lrelu_f(s);
    }
    __syncthreads();
    {
        const int b = tid >> 6, c = tid & 63;
        float s = 0.f;
#pragma unroll
        for (int o = 0; o < 16; o++) s += wa2[c * 16 + o] * a1s[b * 16 + o];
        a2o[tid] = 1.f / (1.f + expf(-s));
    }
}

// ---------------- depthwise 3x3 with folded attention scale ----------------
__global__ __launch_bounds__(256) void k_dw(const float* __restrict__ xp, const float* __restrict__ a2,
    const float* __restrict__ wref, const float* __restrict__ bref, float* __restrict__ out)
{
    const int tid = threadIdx.x;
    const int img = blockIdx.x >> 8, y = blockIdx.x & 255;
    const int c = img & 63;
    const float* src = xp + (size_t)img * HW;
    float wv[9];
#pragma unroll
    for (int k = 0; k < 9; k++) wv[k] = wref[c * 9 + k];
    const float scale = a2[img], bb = bref[c];
    const int xx = tid;
    float s = 0.f;
#pragma unroll
    for (int dy = 0; dy < 3; dy++) {
        const int yy = y + dy - 1;
        if (yy < 0 || yy > 255) continue;
        const float* r = src + (size_t)yy * WIDTH;
#pragma unroll
        for (int dx = 0; dx < 3; dx++) {
            const int xc_ = xx + dx - 1;
            if (xc_ < 0 || xc_ > 255) continue;
            s += wv[dy * 3 + dx] * r[xc_];
        }
    }
    out[(size_t)img * HW + (size_t)y * WIDTH + xx] = bb + scale * s;
}

// ---------------- in-place instance-norm + leaky relu ----------------
__global__ __launch_bounds__(256) void k_norm(float* __restrict__ buf, const float* __restrict__ st)
{
    const size_t i = (size_t)blockIdx.x * 256 + threadIdx.x;   // float4 index
    const int img = (int)(i >> 14);                            // 16384 float4 per image
    const float m = st[img * 2], s = st[img * 2 + 1];
    float4 v = ((float4*)buf)[i];
    v.x = lrelu_f((v.x - m) * s);
    v.y = lrelu_f((v.y - m) * s);
    v.z = lrelu_f((v.z - m) * s);
    v.w = lrelu_f((v.w - m) * s);
    ((float4*)buf)[i] = v;
}

// ---------------- Dirichlet kernel tables ----------------
__global__ void k_tables(float* __restrict__ kr2, float* __restrict__ ki2)
{
    const int t = blockIdx.x * 256 + threadIdx.x;
    if (t < 512) {
        const int tm = t & 255;
        const double PI = 3.14159265358979323846;
        const double th = 2.0 * PI * (double)tm / 256.0;
        double sr = 1.0;
        for (int k = 1; k <= 37; k++) sr += 2.0 * cos((double)k * th);
        sr += cos(38.0 * th);
        kr2[t] = (float)(sr / 256.0);
        ki2[t] = (float)(-sin(38.0 * th) / 256.0);
    }
}

// ---------------- DFT stage 1: A+iB = K (circ-conv over y) applied to xp ----------------
__global__ __launch_bounds__(256) void k_dft1(const float* __restrict__ xp,
    const float* __restrict__ kr2, const float* __restrict__ ki2,
    float* __restrict__ A, float* __restrict__ Bm)
{
    __shared__ float X[32][256];
    const int tid = threadIdx.x;
    const int img = blockIdx.x >> 3, strip = blockIdx.x & 7;
    const int yg = tid >> 6, xg = tid & 63;
    const int y0 = strip * 32 + yg * 8, x0 = xg * 4;
    const float* src = xp + (size_t)img * HW;

    float aR[8][4], aI[8][4];
#pragma unroll
    for (int j = 0; j < 8; j++)
#pragma unroll
        for (int i = 0; i < 4; i++) { aR[j][i] = 0.f; aI[j][i] = 0.f; }

    for (int ch = 0; ch < 8; ch++) {
        __syncthreads();
#pragma unroll
        for (int k = 0; k < 8; k++) {
            const int f4 = k * 256 + tid;
            const int row = f4 >> 6, col = (f4 & 63) * 4;
            *(float4*)&X[row][col] = *(const float4*)(src + (size_t)(ch * 32 + row) * WIDTH + col);
        }
        __syncthreads();
        for (int yl = 0; yl < 32; yl++) {
            const int yp = ch * 32 + yl;
            const int base = __builtin_amdgcn_readfirstlane(y0 - yp + 256);
            const float4 xv = *(const float4*)&X[yl][x0];
#pragma unroll
            for (int j = 0; j < 8; j++) {
                const float wr = kr2[base + j];
                const float wi = ki2[base + j];
                aR[j][0] += wr * xv.x; aR[j][1] += wr * xv.y; aR[j][2] += wr * xv.z; aR[j][3] += wr * xv.w;
                aI[j][0] += wi * xv.x; aI[j][1] += wi * xv.y; aI[j][2] += wi * xv.z; aI[j][3] += wi * xv.w;
            }
        }
    }
#pragma unroll
    for (int j = 0; j < 8; j++) {
        const size_t off = (size_t)img * HW + (size_t)(y0 + j) * WIDTH + x0;
        *(float4*)(A  + off) = make_float4(aR[j][0], aR[j][1], aR[j][2], aR[j][3]);
        *(float4*)(Bm + off) = make_float4(aI[j][0], aI[j][1], aI[j][2], aI[j][3]);
    }
}

// ---------------- DFT stage 2: low = Re(K circ-conv over x of (A+iB)) ----------------
__global__ __launch_bounds__(256) void k_dft2(const float* __restrict__ A,
    const float* __restrict__ Bm, const float* __restrict__ kr2, const float* __restrict__ ki2,
    float* __restrict__ low)
{
    __shared__ float tR[512], tI[512];
    const int tid = threadIdx.x;
    for (int t = tid; t < 512; t += 256) { tR[t] = kr2[t]; tI[t] = ki2[t]; }
    __syncthreads();
    const int img = blockIdx.x >> 3, strip = blockIdx.x & 7;
    const int yg = tid >> 6, xg = tid & 63;
    const int y0 = strip * 32 + yg * 8;
    const float* Ab = A  + (size_t)img * HW;
    const float* Bb = Bm + (size_t)img * HW;

    float acc[8][4];
#pragma unroll
    for (int j = 0; j < 8; j++)
#pragma unroll
        for (int i = 0; i < 4; i++) acc[j][i] = 0.f;

    for (int xq = 0; xq < 256; xq++) {
        const int rbase = __builtin_amdgcn_readfirstlane(y0 * WIDTH + xq);
        float av[8], bv[8];
#pragma unroll
        for (int j = 0; j < 8; j++) { av[j] = Ab[rbase + j * WIDTH]; bv[j] = Bb[rbase + j * WIDTH]; }
#pragma unroll
        for (int i = 0; i < 4; i++) {
            const int x = xg + 64 * i;
            const float wr = tR[x - xq + 256];
            const float wi = tI[x - xq + 256];
#pragma unroll
            for (int j = 0; j < 8; j++) acc[j][i] += wr * av[j] - wi * bv[j];
        }
    }
#pragma unroll
    for (int j = 0; j < 8; j++)
#pragma unroll
        for (int i = 0; i < 4; i++)
            low[(size_t)img * HW + (size_t)(y0 + j) * WIDTH + xg + 64 * i] = acc[j][i];
}

// ---------------- W_eff = collapse(grouped 3x3, 1x1) ----------------
__global__ __launch_bounds__(256) void k_weff(const float* __restrict__ w_u1,
    const float* __restrict__ w_con, float* __restrict__ weff)
{
    const int idx = blockIdx.x * 256 + threadIdx.x;   // 64*128*9 = 73728
    if (idx >= 64 * 128 * 9) return;
    const int pos = idx % 9;
    const int g = (idx / 9) & 127;
    const int o = idx / 1152;
    float s = 0.f;
#pragma unroll
    for (int j = 0; j < 4; j++) s += w_u1[o * 512 + g * 4 + j] * w_con[(g * 4 + j) * 9 + pos];
    weff[idx] = s;
}

// ---------------- generic conv: CIN -> 64, KS in {1,3}, optional residual add ----------------
// Block: one (b, y) row x 32 output channels. Threads: 8 o-groups (4 out each) x
// 32 x-groups (8 px each) -> 32 accumulators/thread. Weights in LDS with o
// innermost: each thread's 4 weights = one broadcast ds_read_b128 per 32 FMAs.
// R2 post-mortem: full unroll of the cc loop let the scheduler hoist all global
// loads -> VGPR=256 cap + 2 GB scratch writes. Bound the window: unroll 2 +
// __launch_bounds__(256,3) (VGPR <= ~168, 12 waves/CU).
template<int CIN, int CHUNK, int KS, bool ADD>
__global__ __launch_bounds__(256, 3) void k_conv(const float* __restrict__ in0,
    const float* __restrict__ in1, const float* __restrict__ wt,
    const float* __restrict__ bias, const float* __restrict__ addsrc,
    float* __restrict__ out)
{
    __shared__ float wl[CHUNK][KS * KS][32];
    const int tid = threadIdx.x;
    const int og = tid >> 5, xg = tid & 31;
    const int half = blockIdx.x & 1;
    const int y = (blockIdx.x >> 1) & 255;
    const int b = blockIdx.x >> 9;
    const int o_base = half * 32;
    const int o0l = og * 4;            // local output within the 32-wide half
    const int x0 = xg * 8;
    constexpr int IC0 = (CIN == 128) ? 64 : CIN;   // channels held by in0 per batch

    float acc[4][8];
#pragma unroll
    for (int i = 0; i < 4; i++)
#pragma unroll
        for (int j = 0; j < 8; j++) acc[i][j] = 0.f;

    for (int c0 = 0; c0 < CIN; c0 += CHUNK) {
        __syncthreads();
        for (int idx = tid; idx < CHUNK * KS * KS * 32; idx += 256) {
            const int o = idx & 31;
            const int rest = idx >> 5;
            const int pos = rest % (KS * KS);
            const int cc = rest / (KS * KS);
            wl[cc][pos][o] = wt[((size_t)(o_base + o) * CIN + c0 + cc) * (KS * KS) + pos];
        }
        __syncthreads();
#pragma unroll 2
        for (int cc = 0; cc < CHUNK; cc++) {
            const int c = c0 + cc;
            const float* src = (CIN == 128 && c >= 64)
                ? (in1 + ((size_t)(b * 64 + (c - 64))) * HW)
                : (in0 + ((size_t)b * IC0 + c) * HW);
            if constexpr (KS == 3) {
#pragma unroll
                for (int dy = 0; dy < 3; dy++) {
                    const int yy = y + dy - 1;
                    float vv[10];
                    if (yy >= 0 && yy < 256) {
                        const float* r = src + (size_t)yy * WIDTH;
                        vv[0] = (x0 > 0) ? r[x0 - 1] : 0.f;
                        const float4 m0 = *(const float4*)(r + x0);
                        const float4 m1 = *(const float4*)(r + x0 + 4);
                        vv[1] = m0.x; vv[2] = m0.y; vv[3] = m0.z; vv[4] = m0.w;
                        vv[5] = m1.x; vv[6] = m1.y; vv[7] = m1.z; vv[8] = m1.w;
                        vv[9] = (x0 < 248) ? r[x0 + 8] : 0.f;
                    } else {
#pragma unroll
                        for (int q = 0; q < 10; q++) vv[q] = 0.f;
                    }
#pragma unroll
                    for (int dx = 0; dx < 3; dx++) {
                        const float4 w4 = *(const float4*)&wl[cc][dy * 3 + dx][o0l];
                        const float wv[4] = { w4.x, w4.y, w4.z, w4.w };
#pragma unroll
                        for (int oi = 0; oi < 4; oi++)
#pragma unroll
                            for (int px = 0; px < 8; px++)
                                acc[oi][px] += wv[oi] * vv[px + dx];
                    }
                }
            } else {
                const float4 m0 = *(const float4*)(src + (size_t)y * WIDTH + x0);
                const float4 m1 = *(const float4*)(src + (size_t)y * WIDTH + x0 + 4);
                const float vv[8] = { m0.x, m0.y, m0.z, m0.w, m1.x, m1.y, m1.z, m1.w };
                const float4 w4 = *(const float4*)&wl[cc][0][o0l];
                const float wv[4] = { w4.x, w4.y, w4.z, w4.w };
#pragma unroll
                for (int oi = 0; oi < 4; oi++)
#pragma unroll
                    for (int px = 0; px < 8; px++)
                        acc[oi][px] += wv[oi] * vv[px];
            }
        }
    }
#pragma unroll
    for (int oi = 0; oi < 4; oi++) {
        const int o = o_base + o0l + oi;
        const float bv = bias[o];
        const size_t off = ((size_t)(b * 64 + o)) * HW + (size_t)y * WIDTH + x0;
        float4 r0, r1;
        r0.x = acc[oi][0] + bv; r0.y = acc[oi][1] + bv; r0.z = acc[oi][2] + bv; r0.w = acc[oi][3] + bv;
        r1.x = acc[oi][4] + bv; r1.y = acc[oi][5] + bv; r1.z = acc[oi][6] + bv; r1.w = acc[oi][7] + bv;
        if constexpr (ADD) {
            const float4 a0 = *(const float4*)(addsrc + off);
            const float4 a1 = *(const float4*)(addsrc + off + 4);
            r0.x += a0.x; r0.y += a0.y; r0.z += a0.z; r0.w += a0.w;
            r1.x += a1.x; r1.y += a1.y; r1.z += a1.z; r1.w += a1.w;
        }
        *(float4*)(out + off) = r0;
        *(float4*)(out + off + 4) = r1;
    }
}

// ---------------- 2x2 max pool ----------------
__global__ __launch_bounds__(256) void k_maxpool(const float* __restrict__ feat, float* __restrict__ out)
{
    const int idx = blockIdx.x * 256 + threadIdx.x;      // 4*64*128*128
    const int xo = idx & 127;
    const int yo = (idx >> 7) & 127;
    const int img = idx >> 14;
    const float* p = feat + (size_t)img * HW + (size_t)(yo * 2) * WIDTH + xo * 2;
    out[idx] = fmaxf(fmaxf(p[0], p[1]), fmaxf(p[WIDTH], p[WIDTH + 1]));
}

extern "C" void kernel_launch(void* const* d_in, const int* in_sizes, int n_in,
                              void* d_out, int out_size, void* d_ws, size_t ws_size,
                              hipStream_t stream)
{
    const float* x      = (const float*)d_in[0];
    const float* w_proj = (const float*)d_in[1];
    const float* b_proj = (const float*)d_in[2];
    const float* w_a1   = (const float*)d_in[3];
    const float* w_a2   = (const float*)d_in[4];
    const float* w_ref  = (const float*)d_in[5];
    const float* b_ref  = (const float*)d_in[6];
    const float* w_fuse = (const float*)d_in[7];
    const float* b_fuse = (const float*)d_in[8];
    const float* w_con  = (const float*)d_in[9];
    const float* w_u1   = (const float*)d_in[10];
    const float* b_u1   = (const float*)d_in[11];
    const float* w_u2   = (const float*)d_in[12];
    const float* b_u2   = (const float*)d_in[13];
    const float* w_sc   = (const float*)d_in[14];
    const float* b_sc   = (const float*)d_in[15];

    float* wsf  = (float*)d_ws;
    float* buf0 = wsf;                       // xp -> low -> u2raw/u_b
    float* buf1 = wsf + (size_t)IMG;         // xw (normalized in place)
    float* buf2 = wsf + (size_t)2 * IMG;     // A -> low_f (normalized in place)
    float* aux  = wsf + (size_t)3 * IMG;
    float* st0  = aux;                       // 512 each (mean, inv_std interleaved)
    float* st1  = aux + 512;
    float* st2  = aux + 1024;
    float* st3  = aux + 1536;
    float* st4  = aux + 2048;
    float* a2b  = aux + 2560;                // 256
    float* kr2  = aux + 2816;                // 512
    float* ki2  = aux + 3328;                // 512
    float* weff = aux + 3840;                // 73728

    float* fout = (float*)d_out;             // B -> u1raw/u_a -> feat
    float* pout = fout + (size_t)IMG;        // pooled

    k_tables<<<2, 256, 0, stream>>>(kr2, ki2);
    k_conv<3, 3, 3, false><<<2048, 256, 0, stream>>>(x, nullptr, w_proj, b_proj, nullptr, buf0);
    k_stats<<<NIMG, 256, 0, stream>>>(buf0, st0);
    k_attention<<<1, 256, 0, stream>>>(st0, w_a1, w_a2, a2b);
    k_dw<<<65536, 256, 0, stream>>>(buf0, a2b, w_ref, b_ref, buf1);
    k_stats<<<NIMG, 256, 0, stream>>>(buf1, st1);
    k_norm<<<16384, 256, 0, stream>>>(buf1, st1);
    k_dft1<<<2048, 256, 0, stream>>>(buf0, kr2, ki2, buf2, fout);
    k_dft2<<<2048, 256, 0, stream>>>(buf2, fout, kr2, ki2, buf0);
    k_conv<64, 8, 1, false><<<2048, 256, 0, stream>>>(buf0, nullptr, w_fuse, b_fuse, nullptr, buf2);
    k_stats<<<NIMG, 256, 0, stream>>>(buf2, st2);
    k_norm<<<16384, 256, 0, stream>>>(buf2, st2);
    k_weff<<<288, 256, 0, stream>>>(w_u1, w_con, weff);
    k_conv<128, 8, 3, false><<<2048, 256, 0, stream>>>(buf1, buf2, weff, b_u1, nullptr, fout);
    k_stats<<<NIMG, 256, 0, stream>>>(fout, st3);
    k_norm<<<16384, 256, 0, stream>>>(fout, st3);
    k_conv<64, 8, 3, false><<<2048, 256, 0, stream>>>(fout, nullptr, w_u2, b_u2, nullptr, buf0);
    k_stats<<<NIMG, 256, 0, stream>>>(buf0, st4);
    k_norm<<<16384, 256, 0, stream>>>(buf0, st4);
    k_conv<128, 8, 1, true><<<2048, 256, 0, stream>>>(buf1, buf2, w_sc, b_sc, buf0, fout);
    k_maxpool<<<16384, 256, 0, stream>>>(fout, pout);
}

// Round 4
// 1309.131 us; speedup vs baseline: 10.2866x; 2.3737x over previous
//
#include <hip/hip_runtime.h>
#include <hip/hip_bf16.h>

#define WIDTH 256
#define HW 65536
#define IMG 16777216   // 4*64*HW
#define NIMG 256

typedef __attribute__((ext_vector_type(8))) short bf8v;   // 8 bf16 = 4 VGPR (MFMA A/B frag)
typedef __attribute__((ext_vector_type(4))) float f4v;    // 4 f32 (MFMA C/D frag)

__device__ __forceinline__ float lrelu_f(float v){ return v > 0.f ? v : 0.01f*v; }
__device__ __forceinline__ unsigned short bf16u(float v){
    __hip_bfloat16 h = __float2bfloat16(v);
    return *(unsigned short*)&h;
}

// ---------------- per-image stats: mean + inv_std ----------------
__global__ __launch_bounds__(256) void k_stats(const float* __restrict__ src, float* __restrict__ st)
{
    const float* p = src + (size_t)blockIdx.x * HW;
    float s = 0.f, s2 = 0.f;
    for (int i = threadIdx.x; i < HW / 4; i += 256) {
        const float4 v = ((const float4*)p)[i];
        s  += v.x + v.y + v.z + v.w;
        s2 += v.x * v.x + v.y * v.y + v.z * v.z + v.w * v.w;
    }
#pragma unroll
    for (int off = 32; off > 0; off >>= 1) {
        s  += __shfl_down(s, off, 64);
        s2 += __shfl_down(s2, off, 64);
    }
    __shared__ float ls[4], ls2[4];
    const int wid = threadIdx.x >> 6, lane = threadIdx.x & 63;
    if (lane == 0) { ls[wid] = s; ls2[wid] = s2; }
    __syncthreads();
    if (threadIdx.x == 0) {
        float S = 0.f, S2 = 0.f;
#pragma unroll
        for (int w = 0; w < 4; w++) { S += ls[w]; S2 += ls2[w]; }
        const float m = S / 65536.f;
        const float var = S2 / 65536.f - m * m;
        st[blockIdx.x * 2]     = m;
        st[blockIdx.x * 2 + 1] = rsqrtf(var + 1e-5f);
    }
}

// ---------------- attention MLP (single block) ----------------
__global__ __launch_bounds__(256) void k_attention(const float* __restrict__ st0,
    const float* __restrict__ wa1, const float* __restrict__ wa2, float* __restrict__ a2o)
{
    __shared__ float a1s[64];
    const int tid = threadIdx.x;
    if (tid < 64) {
        const int b = tid >> 4, o = tid & 15;
        float s = 0.f;
        for (int c = 0; c < 64; c++) s += wa1[o * 64 + c] * st0[(b * 64 + c) * 2];
        a1s[b * 16 + o] = lrelu_f(s);
    }
    __syncthreads();
    {
        const int b = tid >> 6, c = tid & 63;
        float s = 0.f;
#pragma unroll
        for (int o = 0; o < 16; o++) s += wa2[c * 16 + o] * a1s[b * 16 + o];
        a2o[tid] = 1.f / (1.f + expf(-s));
    }
}

// ---------------- depthwise 3x3 with folded attention scale ----------------
__global__ __launch_bounds__(256) void k_dw(const float* __restrict__ xp, const float* __restrict__ a2,
    const float* __restrict__ wref, const float* __restrict__ bref, float* __restrict__ out)
{
    const int tid = threadIdx.x;
    const int img = blockIdx.x >> 8, y = blockIdx.x & 255;
    const int c = img & 63;
    const float* src = xp + (size_t)img * HW;
    float wv[9];
#pragma unroll
    for (int k = 0; k < 9; k++) wv[k] = wref[c * 9 + k];
    const float scale = a2[img], bb = bref[c];
    const int xx = tid;
    float s = 0.f;
#pragma unroll
    for (int dy = 0; dy < 3; dy++) {
        const int yy = y + dy - 1;
        if (yy < 0 || yy > 255) continue;
        const float* r = src + (size_t)yy * WIDTH;
#pragma unroll
        for (int dx = 0; dx < 3; dx++) {
            const int xc_ = xx + dx - 1;
            if (xc_ < 0 || xc_ > 255) continue;
            s += wv[dy * 3 + dx] * r[xc_];
        }
    }
    out[(size_t)img * HW + (size_t)y * WIDTH + xx] = bb + scale * s;
}

// ---------------- in-place instance-norm + leaky relu ----------------
__global__ __launch_bounds__(256) void k_norm(float* __restrict__ buf, const float* __restrict__ st)
{
    const size_t i = (size_t)blockIdx.x * 256 + threadIdx.x;   // float4 index
    const int img = (int)(i >> 14);                            // 16384 float4 per image
    const float m = st[img * 2], s = st[img * 2 + 1];
    float4 v = ((float4*)buf)[i];
    v.x = lrelu_f((v.x - m) * s);
    v.y = lrelu_f((v.y - m) * s);
    v.z = lrelu_f((v.z - m) * s);
    v.w = lrelu_f((v.w - m) * s);
    ((float4*)buf)[i] = v;
}

// ---------------- Dirichlet kernel tables ----------------
__global__ void k_tables(float* __restrict__ kr2, float* __restrict__ ki2)
{
    const int t = blockIdx.x * 256 + threadIdx.x;
    if (t < 512) {
        const int tm = t & 255;
        const double PI = 3.14159265358979323846;
        const double th = 2.0 * PI * (double)tm / 256.0;
        double sr = 1.0;
        for (int k = 1; k <= 37; k++) sr += 2.0 * cos((double)k * th);
        sr += cos(38.0 * th);
        kr2[t] = (float)(sr / 256.0);
        ki2[t] = (float)(-sin(38.0 * th) / 256.0);
    }
}

// ---------------- DFT stage 1 ----------------
__global__ __launch_bounds__(256) void k_dft1(const float* __restrict__ xp,
    const float* __restrict__ kr2, const float* __restrict__ ki2,
    float* __restrict__ A, float* __restrict__ Bm)
{
    __shared__ float X[32][256];
    const int tid = threadIdx.x;
    const int img = blockIdx.x >> 3, strip = blockIdx.x & 7;
    const int yg = tid >> 6, xg = tid & 63;
    const int y0 = strip * 32 + yg * 8, x0 = xg * 4;
    const float* src = xp + (size_t)img * HW;

    float aR[8][4], aI[8][4];
#pragma unroll
    for (int j = 0; j < 8; j++)
#pragma unroll
        for (int i = 0; i < 4; i++) { aR[j][i] = 0.f; aI[j][i] = 0.f; }

    for (int ch = 0; ch < 8; ch++) {
        __syncthreads();
#pragma unroll
        for (int k = 0; k < 8; k++) {
            const int f4 = k * 256 + tid;
            const int row = f4 >> 6, col = (f4 & 63) * 4;
            *(float4*)&X[row][col] = *(const float4*)(src + (size_t)(ch * 32 + row) * WIDTH + col);
        }
        __syncthreads();
        for (int yl = 0; yl < 32; yl++) {
            const int yp = ch * 32 + yl;
            const int base = __builtin_amdgcn_readfirstlane(y0 - yp + 256);
            const float4 xv = *(const float4*)&X[yl][x0];
#pragma unroll
            for (int j = 0; j < 8; j++) {
                const float wr = kr2[base + j];
                const float wi = ki2[base + j];
                aR[j][0] += wr * xv.x; aR[j][1] += wr * xv.y; aR[j][2] += wr * xv.z; aR[j][3] += wr * xv.w;
                aI[j][0] += wi * xv.x; aI[j][1] += wi * xv.y; aI[j][2] += wi * xv.z; aI[j][3] += wi * xv.w;
            }
        }
    }
#pragma unroll
    for (int j = 0; j < 8; j++) {
        const size_t off = (size_t)img * HW + (size_t)(y0 + j) * WIDTH + x0;
        *(float4*)(A  + off) = make_float4(aR[j][0], aR[j][1], aR[j][2], aR[j][3]);
        *(float4*)(Bm + off) = make_float4(aI[j][0], aI[j][1], aI[j][2], aI[j][3]);
    }
}

// ---------------- DFT stage 2 ----------------
__global__ __launch_bounds__(256) void k_dft2(const float* __restrict__ A,
    const float* __restrict__ Bm, const float* __restrict__ kr2, const float* __restrict__ ki2,
    float* __restrict__ low)
{
    __shared__ float tR[512], tI[512];
    const int tid = threadIdx.x;
    for (int t = tid; t < 512; t += 256) { tR[t] = kr2[t]; tI[t] = ki2[t]; }
    __syncthreads();
    const int img = blockIdx.x >> 3, strip = blockIdx.x & 7;
    const int yg = tid >> 6, xg = tid & 63;
    const int y0 = strip * 32 + yg * 8;
    const float* Ab = A  + (size_t)img * HW;
    const float* Bb = Bm + (size_t)img * HW;

    float acc[8][4];
#pragma unroll
    for (int j = 0; j < 8; j++)
#pragma unroll
        for (int i = 0; i < 4; i++) acc[j][i] = 0.f;

    for (int xq = 0; xq < 256; xq++) {
        const int rbase = __builtin_amdgcn_readfirstlane(y0 * WIDTH + xq);
        float av[8], bv[8];
#pragma unroll
        for (int j = 0; j < 8; j++) { av[j] = Ab[rbase + j * WIDTH]; bv[j] = Bb[rbase + j * WIDTH]; }
#pragma unroll
        for (int i = 0; i < 4; i++) {
            const int x = xg + 64 * i;
            const float wr = tR[x - xq + 256];
            const float wi = tI[x - xq + 256];
#pragma unroll
            for (int j = 0; j < 8; j++) acc[j][i] += wr * av[j] - wi * bv[j];
        }
    }
#pragma unroll
    for (int j = 0; j < 8; j++)
#pragma unroll
        for (int i = 0; i < 4; i++)
            low[(size_t)img * HW + (size_t)(y0 + j) * WIDTH + xg + 64 * i] = acc[j][i];
}

// ---- W_eff = collapse(grouped 3x3, 1x1) -> bf16 [chunk][pos][oc][ch] ----
__global__ __launch_bounds__(256) void k_weff_bf(const float* __restrict__ w_u1,
    const float* __restrict__ w_con, unsigned short* __restrict__ wbf)
{
    const int f = blockIdx.x * 256 + threadIdx.x;   // 64*128*9 = 73728
    if (f >= 73728) return;
    const int ch = f & 31, oc = (f >> 5) & 63, cp = f >> 11;
    const int pos = cp % 9, cb = cp / 9;
    const int g = cb * 32 + ch;
    float s = 0.f;
#pragma unroll
    for (int j = 0; j < 4; j++) s += w_u1[oc * 512 + g * 4 + j] * w_con[(g * 4 + j) * 9 + pos];
    wbf[f] = bf16u(s);
}

// ---- fp32 OIHW 3x3 weights -> bf16 [chunk][pos][oc][ch] ----
template<int CIN>
__global__ __launch_bounds__(256) void k_wcvt(const float* __restrict__ w, unsigned short* __restrict__ wbf)
{
    const int f = blockIdx.x * 256 + threadIdx.x;   // 64*CIN*9
    if (f >= 64 * CIN * 9) return;
    const int ch = f & 31, oc = (f >> 5) & 63, cp = f >> 11;
    const int pos = cp % 9, cb = cp / 9;
    const int c = cb * 32 + ch;
    wbf[f] = bf16u(w[oc * CIN * 9 + c * 9 + pos]);
}

// ---------------- MFMA 3x3 conv: CIN -> 64 (bf16 in, fp32 acc) ----------------
// Block = (b, 2 output rows), 4 waves; wave = 128 px (8 M-tiles) x 64 oc (4 N-tiles).
// LDS X: [4 rows][260 px][32 ch] bf16, 16B-slot swizzle slot = g ^ ((px>>1)&3)
// (breaks the 64B-px-stride 8-way bank conflict -> free 2-way). Swizzle is
// m-tile-invariant, so tile reads use ds offset immediates. Weights consumed
// per-lane straight from global (4KB/pos, L1-broadcast), no W-LDS, no per-pos sync.
template<int CIN>
__global__ __launch_bounds__(256, 2) void k_mconv(
    const float* __restrict__ in0, const float* __restrict__ in1,
    const unsigned short* __restrict__ wbf, const float* __restrict__ bias,
    float* __restrict__ out)
{
    __shared__ unsigned short Xl[4 * 260 * 32];
    const int tid = threadIdx.x;
    const int lane = tid & 63;
    const int wave = tid >> 6;
    const int b = blockIdx.x >> 7;
    const int y0 = (blockIdx.x & 127) * 2;
    const int row_sel = wave >> 1;          // which of the 2 output rows
    const int px_base = (wave & 1) * 128;   // px half

    for (int i = tid; i < 4 * 260 * 32 / 2; i += 256) ((unsigned int*)Xl)[i] = 0u;

    f4v acc[8][4];
#pragma unroll
    for (int i = 0; i < 8; i++)
#pragma unroll
        for (int n = 0; n < 4; n++) acc[i][n] = (f4v){0.f, 0.f, 0.f, 0.f};

    const int pxl   = px_base + (lane & 15);         // m-index base px
    const int gsl   = lane >> 4;                     // k-group (slot)
    const int wlane = (lane & 15) * 32 + gsl * 8;    // W-frag lane offset (ushorts)

    constexpr int NC = CIN / 32;
#pragma unroll 1
    for (int cb = 0; cb < NC; cb++) {
        const int c0 = cb * 32;
        const float* src = ((CIN == 128 && c0 >= 64) ? in1 : in0)
                           + ((size_t)b * 64 + (c0 & 63)) * HW;
        __syncthreads();
        {   // stage 4 rows x 32 ch x 256 px
            const int px = tid;
            const int px_idx = px + 1;
            const int sw = (px_idx >> 1) & 3;
#pragma unroll 1
            for (int r = 0; r < 4; r++) {
                const int yy = y0 - 1 + r;
                if (yy < 0 || yy > 255) continue;
                const float* rp = src + (size_t)yy * WIDTH + px;
#pragma unroll 4
                for (int d = 0; d < 16; d++) {
                    const float va = rp[(size_t)(2 * d) * HW];
                    const float vb = rp[(size_t)(2 * d + 1) * HW];
                    const unsigned int dw = (unsigned int)bf16u(va)
                                          | ((unsigned int)bf16u(vb) << 16);
                    const int byte = r * 16640 + px_idx * 64
                                   + (((d >> 2) ^ sw) << 4) + ((d & 3) << 2);
                    *(unsigned int*)((char*)Xl + byte) = dw;
                }
            }
        }
        __syncthreads();
#pragma unroll 1
        for (int pos = 0; pos < 9; pos++) {
            const int dy = pos / 3, dx = pos - dy * 3;
            const unsigned short* wp = wbf + (cb * 9 + pos) * 2048 + wlane;
            const bf8v wf0 = *(const bf8v*)(wp);
            const bf8v wf1 = *(const bf8v*)(wp + 512);
            const bf8v wf2 = *(const bf8v*)(wp + 1024);
            const bf8v wf3 = *(const bf8v*)(wp + 1536);
            const int pxe = pxl + dx;
            const int row = row_sel + dy;
            const char* abase = (const char*)Xl + row * 16640 + pxe * 64
                              + ((gsl ^ ((pxe >> 1) & 3)) << 4);
#pragma unroll
            for (int i = 0; i < 8; i++) {
                const bf8v af = *(const bf8v*)(abase + i * 1024);
                acc[i][0] = __builtin_amdgcn_mfma_f32_16x16x32_bf16(af, wf0, acc[i][0], 0, 0, 0);
                acc[i][1] = __builtin_amdgcn_mfma_f32_16x16x32_bf16(af, wf1, acc[i][1], 0, 0, 0);
                acc[i][2] = __builtin_amdgcn_mfma_f32_16x16x32_bf16(af, wf2, acc[i][2], 0, 0, 0);
                acc[i][3] = __builtin_amdgcn_mfma_f32_16x16x32_bf16(af, wf3, acc[i][3], 0, 0, 0);
            }
        }
    }
    // epilogue: D lane holds 4 consecutive px (m = (lane>>4)*4 + r) at oc = n*16 + (lane&15)
    const int yrow = y0 + row_sel;
#pragma unroll
    for (int n = 0; n < 4; n++) {
        const float bv = bias[n * 16 + (lane & 15)];
        float* po = out + ((size_t)(b * 64) + n * 16 + (lane & 15)) * HW
                  + (size_t)yrow * WIDTH + px_base + (lane >> 4) * 4;
#pragma unroll
        for (int i = 0; i < 8; i++) {
            const f4v a = acc[i][n];
            const float4 v = make_float4(a[0] + bv, a[1] + bv, a[2] + bv, a[3] + bv);
            *(float4*)(po + i * 16) = v;
        }
    }
}

// ---------------- generic fp32 conv (proj + 1x1s) ----------------
template<int CIN, int CHUNK, int KS, bool ADD>
__global__ __launch_bounds__(256, 3) void k_conv(const float* __restrict__ in0,
    const float* __restrict__ in1, const float* __restrict__ wt,
    const float* __restrict__ bias, const float* __restrict__ addsrc,
    float* __restrict__ out)
{
    __shared__ float wl[CHUNK][KS * KS][32];
    const int tid = threadIdx.x;
    const int og = tid >> 5, xg = tid & 31;
    const int half = blockIdx.x & 1;
    const int y = (blockIdx.x >> 1) & 255;
    const int b = blockIdx.x >> 9;
    const int o_base = half * 32;
    const int o0l = og * 4;
    const int x0 = xg * 8;
    constexpr int IC0 = (CIN == 128) ? 64 : CIN;

    float acc[4][8];
#pragma unroll
    for (int i = 0; i < 4; i++)
#pragma unroll
        for (int j = 0; j < 8; j++) acc[i][j] = 0.f;

    for (int c0 = 0; c0 < CIN; c0 += CHUNK) {
        __syncthreads();
        for (int idx = tid; idx < CHUNK * KS * KS * 32; idx += 256) {
            const int o = idx & 31;
            const int rest = idx >> 5;
            const int pos = rest % (KS * KS);
            const int cc = rest / (KS * KS);
            wl[cc][pos][o] = wt[((size_t)(o_base + o) * CIN + c0 + cc) * (KS * KS) + pos];
        }
        __syncthreads();
#pragma unroll 2
        for (int cc = 0; cc < CHUNK; cc++) {
            const int c = c0 + cc;
            const float* src = (CIN == 128 && c >= 64)
                ? (in1 + ((size_t)(b * 64 + (c - 64))) * HW)
                : (in0 + ((size_t)b * IC0 + c) * HW);
            if constexpr (KS == 3) {
#pragma unroll
                for (int dy = 0; dy < 3; dy++) {
                    const int yy = y + dy - 1;
                    float vv[10];
                    if (yy >= 0 && yy < 256) {
                        const float* r = src + (size_t)yy * WIDTH;
                        vv[0] = (x0 > 0) ? r[x0 - 1] : 0.f;
                        const float4 m0 = *(const float4*)(r + x0);
                        const float4 m1 = *(const float4*)(r + x0 + 4);
                        vv[1] = m0.x; vv[2] = m0.y; vv[3] = m0.z; vv[4] = m0.w;
                        vv[5] = m1.x; vv[6] = m1.y; vv[7] = m1.z; vv[8] = m1.w;
                        vv[9] = (x0 < 248) ? r[x0 + 8] : 0.f;
                    } else {
#pragma unroll
                        for (int q = 0; q < 10; q++) vv[q] = 0.f;
                    }
#pragma unroll
                    for (int dx = 0; dx < 3; dx++) {
                        const float4 w4 = *(const float4*)&wl[cc][dy * 3 + dx][o0l];
                        const float wv[4] = { w4.x, w4.y, w4.z, w4.w };
#pragma unroll
                        for (int oi = 0; oi < 4; oi++)
#pragma unroll
                            for (int px = 0; px < 8; px++)
                                acc[oi][px] += wv[oi] * vv[px + dx];
                    }
                }
            } else {
                const float4 m0 = *(const float4*)(src + (size_t)y * WIDTH + x0);
                const float4 m1 = *(const float4*)(src + (size_t)y * WIDTH + x0 + 4);
                const float vv[8] = { m0.x, m0.y, m0.z, m0.w, m1.x, m1.y, m1.z, m1.w };
                const float4 w4 = *(const float4*)&wl[cc][0][o0l];
                const float wv[4] = { w4.x, w4.y, w4.z, w4.w };
#pragma unroll
                for (int oi = 0; oi < 4; oi++)
#pragma unroll
                    for (int px = 0; px < 8; px++)
                        acc[oi][px] += wv[oi] * vv[px];
            }
        }
    }
#pragma unroll
    for (int oi = 0; oi < 4; oi++) {
        const int o = o_base + o0l + oi;
        const float bv = bias[o];
        const size_t off = ((size_t)(b * 64 + o)) * HW + (size_t)y * WIDTH + x0;
        float4 r0, r1;
        r0.x = acc[oi][0] + bv; r0.y = acc[oi][1] + bv; r0.z = acc[oi][2] + bv; r0.w = acc[oi][3] + bv;
        r1.x = acc[oi][4] + bv; r1.y = acc[oi][5] + bv; r1.z = acc[oi][6] + bv; r1.w = acc[oi][7] + bv;
        if constexpr (ADD) {
            const float4 a0 = *(const float4*)(addsrc + off);
            const float4 a1 = *(const float4*)(addsrc + off + 4);
            r0.x += a0.x; r0.y += a0.y; r0.z += a0.z; r0.w += a0.w;
            r1.x += a1.x; r1.y += a1.y; r1.z += a1.z; r1.w += a1.w;
        }
        *(float4*)(out + off) = r0;
        *(float4*)(out + off + 4) = r1;
    }
}

// ---------------- 2x2 max pool ----------------
__global__ __launch_bounds__(256) void k_maxpool(const float* __restrict__ feat, float* __restrict__ out)
{
    const int idx = blockIdx.x * 256 + threadIdx.x;
    const int xo = idx & 127;
    const int yo = (idx >> 7) & 127;
    const int img = idx >> 14;
    const float* p = feat + (size_t)img * HW + (size_t)(yo * 2) * WIDTH + xo * 2;
    out[idx] = fmaxf(fmaxf(p[0], p[1]), fmaxf(p[WIDTH], p[WIDTH + 1]));
}

extern "C" void kernel_launch(void* const* d_in, const int* in_sizes, int n_in,
                              void* d_out, int out_size, void* d_ws, size_t ws_size,
                              hipStream_t stream)
{
    const float* x      = (const float*)d_in[0];
    const float* w_proj = (const float*)d_in[1];
    const float* b_proj = (const float*)d_in[2];
    const float* w_a1   = (const float*)d_in[3];
    const float* w_a2   = (const float*)d_in[4];
    const float* w_ref  = (const float*)d_in[5];
    const float* b_ref  = (const float*)d_in[6];
    const float* w_fuse = (const float*)d_in[7];
    const float* b_fuse = (const float*)d_in[8];
    const float* w_con  = (const float*)d_in[9];
    const float* w_u1   = (const float*)d_in[10];
    const float* b_u1   = (const float*)d_in[11];
    const float* w_u2   = (const float*)d_in[12];
    const float* b_u2   = (const float*)d_in[13];
    const float* w_sc   = (const float*)d_in[14];
    const float* b_sc   = (const float*)d_in[15];

    float* wsf  = (float*)d_ws;
    float* buf0 = wsf;                       // xp -> low -> u2raw/u_b
    float* buf1 = wsf + (size_t)IMG;         // xw (normalized in place)
    float* buf2 = wsf + (size_t)2 * IMG;     // A -> low_f (normalized in place)
    float* aux  = wsf + (size_t)3 * IMG;
    float* st0  = aux;
    float* st1  = aux + 512;
    float* st2  = aux + 1024;
    float* st3  = aux + 1536;
    float* st4  = aux + 2048;
    float* a2b  = aux + 2560;                // 256
    float* kr2  = aux + 2816;                // 512
    float* ki2  = aux + 3328;                // 512
    unsigned short* wbfA = (unsigned short*)(aux + 3840);           // 73728 ushort
    unsigned short* wbfB = (unsigned short*)(aux + 3840 + 36864);   // 36864 ushort

    float* fout = (float*)d_out;             // u1raw/u_a -> feat
    float* pout = fout + (size_t)IMG;        // pooled

    k_tables<<<2, 256, 0, stream>>>(kr2, ki2);
    k_weff_bf<<<288, 256, 0, stream>>>(w_u1, w_con, wbfA);
    k_wcvt<64><<<144, 256, 0, stream>>>(w_u2, wbfB);
    k_conv<3, 3, 3, false><<<2048, 256, 0, stream>>>(x, nullptr, w_proj, b_proj, nullptr, buf0);
    k_stats<<<NIMG, 256, 0, stream>>>(buf0, st0);
    k_attention<<<1, 256, 0, stream>>>(st0, w_a1, w_a2, a2b);
    k_dw<<<65536, 256, 0, stream>>>(buf0, a2b, w_ref, b_ref, buf1);
    k_stats<<<NIMG, 256, 0, stream>>>(buf1, st1);
    k_norm<<<16384, 256, 0, stream>>>(buf1, st1);
    k_dft1<<<2048, 256, 0, stream>>>(buf0, kr2, ki2, buf2, fout);
    k_dft2<<<2048, 256, 0, stream>>>(buf2, fout, kr2, ki2, buf0);
    k_conv<64, 8, 1, false><<<2048, 256, 0, stream>>>(buf0, nullptr, w_fuse, b_fuse, nullptr, buf2);
    k_stats<<<NIMG, 256, 0, stream>>>(buf2, st2);
    k_norm<<<16384, 256, 0, stream>>>(buf2, st2);
    k_mconv<128><<<512, 256, 0, stream>>>(buf1, buf2, wbfA, b_u1, fout);
    k_stats<<<NIMG, 256, 0, stream>>>(fout, st3);
    k_norm<<<16384, 256, 0, stream>>>(fout, st3);
    k_mconv<64><<<512, 256, 0, stream>>>(fout, nullptr, wbfB, b_u2, buf0);
    k_stats<<<NIMG, 256, 0, stream>>>(buf0, st4);
    k_norm<<<16384, 256, 0, stream>>>(buf0, st4);
    k_conv<128, 8, 1, true><<<2048, 256, 0, stream>>>(buf1, buf2, w_sc, b_sc, buf0, fout);
    k_maxpool<<<16384, 256, 0, stream>>>(fout, pout);
}

// Round 5
// 796.249 us; speedup vs baseline: 16.9125x; 1.6441x over previous
//
#include <hip/hip_runtime.h>
#include <hip/hip_bf16.h>

#define WIDTH 256
#define HW 65536
#define IMG 16777216   // 4*64*HW
#define NIMG 256

typedef __attribute__((ext_vector_type(8))) short bf8v;   // 8 bf16 = 4 VGPR (MFMA A/B frag)
typedef __attribute__((ext_vector_type(4))) float f4v;    // 4 f32 (MFMA C/D frag)

__device__ __forceinline__ float lrelu_f(float v){ return v > 0.f ? v : 0.01f*v; }
__device__ __forceinline__ unsigned short bf16u(float v){
    __hip_bfloat16 h = __float2bfloat16(v);
    return *(unsigned short*)&h;
}

// ---------------- per-image stats: mean + inv_std ----------------
__global__ __launch_bounds__(256) void k_stats(const float* __restrict__ src, float* __restrict__ st)
{
    const float* p = src + (size_t)blockIdx.x * HW;
    float s = 0.f, s2 = 0.f;
    for (int i = threadIdx.x; i < HW / 4; i += 256) {
        const float4 v = ((const float4*)p)[i];
        s  += v.x + v.y + v.z + v.w;
        s2 += v.x * v.x + v.y * v.y + v.z * v.z + v.w * v.w;
    }
#pragma unroll
    for (int off = 32; off > 0; off >>= 1) {
        s  += __shfl_down(s, off, 64);
        s2 += __shfl_down(s2, off, 64);
    }
    __shared__ float ls[4], ls2[4];
    const int wid = threadIdx.x >> 6, lane = threadIdx.x & 63;
    if (lane == 0) { ls[wid] = s; ls2[wid] = s2; }
    __syncthreads();
    if (threadIdx.x == 0) {
        float S = 0.f, S2 = 0.f;
#pragma unroll
        for (int w = 0; w < 4; w++) { S += ls[w]; S2 += ls2[w]; }
        const float m = S / 65536.f;
        const float var = S2 / 65536.f - m * m;
        st[blockIdx.x * 2]     = m;
        st[blockIdx.x * 2 + 1] = rsqrtf(var + 1e-5f);
    }
}

// ---------------- attention MLP (single block) ----------------
__global__ __launch_bounds__(256) void k_attention(const float* __restrict__ st0,
    const float* __restrict__ wa1, const float* __restrict__ wa2, float* __restrict__ a2o)
{
    __shared__ float a1s[64];
    const int tid = threadIdx.x;
    if (tid < 64) {
        const int b = tid >> 4, o = tid & 15;
        float s = 0.f;
        for (int c = 0; c < 64; c++) s += wa1[o * 64 + c] * st0[(b * 64 + c) * 2];
        a1s[b * 16 + o] = lrelu_f(s);
    }
    __syncthreads();
    {
        const int b = tid >> 6, c = tid & 63;
        float s = 0.f;
#pragma unroll
        for (int o = 0; o < 16; o++) s += wa2[c * 16 + o] * a1s[b * 16 + o];
        a2o[tid] = 1.f / (1.f + expf(-s));
    }
}

// ---------------- depthwise 3x3 with folded attention scale ----------------
__global__ __launch_bounds__(256) void k_dw(const float* __restrict__ xp, const float* __restrict__ a2,
    const float* __restrict__ wref, const float* __restrict__ bref, float* __restrict__ out)
{
    const int tid = threadIdx.x;
    const int img = blockIdx.x >> 8, y = blockIdx.x & 255;
    const int c = img & 63;
    const float* src = xp + (size_t)img * HW;
    float wv[9];
#pragma unroll
    for (int k = 0; k < 9; k++) wv[k] = wref[c * 9 + k];
    const float scale = a2[img], bb = bref[c];
    const int xx = tid;
    float s = 0.f;
#pragma unroll
    for (int dy = 0; dy < 3; dy++) {
        const int yy = y + dy - 1;
        if (yy < 0 || yy > 255) continue;
        const float* r = src + (size_t)yy * WIDTH;
#pragma unroll
        for (int dx = 0; dx < 3; dx++) {
            const int xc_ = xx + dx - 1;
            if (xc_ < 0 || xc_ > 255) continue;
            s += wv[dy * 3 + dx] * r[xc_];
        }
    }
    out[(size_t)img * HW + (size_t)y * WIDTH + xx] = bb + scale * s;
}

// ---------------- in-place instance-norm + leaky relu ----------------
__global__ __launch_bounds__(256) void k_norm(float* __restrict__ buf, const float* __restrict__ st)
{
    const size_t i = (size_t)blockIdx.x * 256 + threadIdx.x;   // float4 index
    const int img = (int)(i >> 14);                            // 16384 float4 per image
    const float m = st[img * 2], s = st[img * 2 + 1];
    float4 v = ((float4*)buf)[i];
    v.x = lrelu_f((v.x - m) * s);
    v.y = lrelu_f((v.y - m) * s);
    v.z = lrelu_f((v.z - m) * s);
    v.w = lrelu_f((v.w - m) * s);
    ((float4*)buf)[i] = v;
}

// ---------------- Dirichlet kernel tables ----------------
__global__ void k_tables(float* __restrict__ kr2, float* __restrict__ ki2)
{
    const int t = blockIdx.x * 256 + threadIdx.x;
    if (t < 512) {
        const int tm = t & 255;
        const double PI = 3.14159265358979323846;
        const double th = 2.0 * PI * (double)tm / 256.0;
        double sr = 1.0;
        for (int k = 1; k <= 37; k++) sr += 2.0 * cos((double)k * th);
        sr += cos(38.0 * th);
        kr2[t] = (float)(sr / 256.0);
        ki2[t] = (float)(-sin(38.0 * th) / 256.0);
    }
}

// ---- circulant DFT matrices in MFMA-B-frag-friendly layout: KB[n][k] = f(n-k) ----
__global__ __launch_bounds__(256) void k_kmat(const float* __restrict__ kr2, const float* __restrict__ ki2,
    unsigned short* __restrict__ KBr, unsigned short* __restrict__ KBi)
{
    const int n = blockIdx.x, k = threadIdx.x;
    const int d = (n - k) & 255;
    KBr[n * 256 + k] = bf16u(kr2[d]);
    KBi[n * 256 + k] = bf16u(ki2[d]);
}

// ---- fp32 -> bf16 image convert (DFT input) ----
__global__ __launch_bounds__(256) void k_tobf(const float* __restrict__ src, unsigned short* __restrict__ dst)
{
    const size_t idx = (size_t)blockIdx.x * 256 + threadIdx.x;  // 8 elems each, IMG/8 total
    const float4 a = ((const float4*)src)[2 * idx];
    const float4 b = ((const float4*)src)[2 * idx + 1];
    uint4 o;
    o.x = (unsigned int)bf16u(a.x) | ((unsigned int)bf16u(a.y) << 16);
    o.y = (unsigned int)bf16u(a.z) | ((unsigned int)bf16u(a.w) << 16);
    o.z = (unsigned int)bf16u(b.x) | ((unsigned int)bf16u(b.y) << 16);
    o.w = (unsigned int)bf16u(b.z) | ((unsigned int)bf16u(b.w) << 16);
    ((uint4*)dst)[idx] = o;
}

// ---------------- MFMA DFT pass 1 (x-direction): T1{R,I}[x][y] = sum_xq xp[y][xq] * k{r,i}(x-xq) ----
// Per image: 2x2 blocks of 128x128; 4 waves of M64(y) x N64(x); acc 2x[4][4] f4v.
// A-frags: contiguous 16B bf16 reads of xp rows. B-frags: contiguous reads of circulant
// tables (L2-hot, 256 KB). D written transposed ([x][y]) -> contiguous ushort4 stores.
__global__ __launch_bounds__(256, 2) void k_mdft1(const unsigned short* __restrict__ xpb,
    const unsigned short* __restrict__ KBr, const unsigned short* __restrict__ KBi,
    unsigned short* __restrict__ TR, unsigned short* __restrict__ TI)
{
    const int tid = threadIdx.x, lane = tid & 63, wave = tid >> 6;
    const int img = blockIdx.x >> 2;
    const int mb = (blockIdx.x >> 1) & 1, nb = blockIdx.x & 1;
    const int M0 = mb * 128 + (wave >> 1) * 64;      // y-base
    const int N0 = nb * 128 + (wave & 1) * 64;       // x-base
    const int lrow = lane & 15, lk = lane >> 4;
    const unsigned short* Xb = xpb + (size_t)img * HW;

    f4v aR[4][4], aI[4][4];
#pragma unroll
    for (int m = 0; m < 4; m++)
#pragma unroll
        for (int n = 0; n < 4; n++) { aR[m][n] = (f4v){0,0,0,0}; aI[m][n] = (f4v){0,0,0,0}; }

#pragma unroll 1
    for (int k0 = 0; k0 < 256; k0 += 32) {
        bf8v af[4];
#pragma unroll
        for (int m = 0; m < 4; m++)
            af[m] = *(const bf8v*)(Xb + (M0 + m * 16 + lrow) * 256 + k0 + lk * 8);
#pragma unroll
        for (int n = 0; n < 4; n++) {
            const int xcol = N0 + n * 16 + lrow;
            const bf8v br = *(const bf8v*)(KBr + xcol * 256 + k0 + lk * 8);
            const bf8v bi = *(const bf8v*)(KBi + xcol * 256 + k0 + lk * 8);
#pragma unroll
            for (int m = 0; m < 4; m++) {
                aR[m][n] = __builtin_amdgcn_mfma_f32_16x16x32_bf16(af[m], br, aR[m][n], 0, 0, 0);
                aI[m][n] = __builtin_amdgcn_mfma_f32_16x16x32_bf16(af[m], bi, aI[m][n], 0, 0, 0);
            }
        }
    }
    // D[m=y][n=x]: lane col x = N0+n*16+lrow, rows y = M0+m*16+lk*4+0..3 -> T[x][y] ushort4
#pragma unroll
    for (int n = 0; n < 4; n++) {
        const size_t xoff = (size_t)img * HW + (size_t)(N0 + n * 16 + lrow) * 256;
#pragma unroll
        for (int m = 0; m < 4; m++) {
            const size_t off = xoff + M0 + m * 16 + lk * 4;
            const f4v r = aR[m][n], ii = aI[m][n];
            ushort4 ur, ui;
            ur.x = bf16u(r[0]); ur.y = bf16u(r[1]); ur.z = bf16u(r[2]); ur.w = bf16u(r[3]);
            ui.x = bf16u(ii[0]); ui.y = bf16u(ii[1]); ui.z = bf16u(ii[2]); ui.w = bf16u(ii[3]);
            *(ushort4*)(TR + off) = ur;
            *(ushort4*)(TI + off) = ui;
        }
    }
}

// ---------------- MFMA DFT pass 2 (y-direction): low[y][x] = sum_yp kr(y-yp)T1R[yp][x] - ki(y-yp)T1I[yp][x] ----
__global__ __launch_bounds__(256, 2) void k_mdft2(const unsigned short* __restrict__ TR,
    const unsigned short* __restrict__ TI, const unsigned short* __restrict__ KBr,
    const unsigned short* __restrict__ KBi, float* __restrict__ low)
{
    const int tid = threadIdx.x, lane = tid & 63, wave = tid >> 6;
    const int img = blockIdx.x >> 2;
    const int mb = (blockIdx.x >> 1) & 1, nb = blockIdx.x & 1;
    const int M0 = mb * 128 + (wave >> 1) * 64;      // x-base (rows of T1)
    const int N0 = nb * 128 + (wave & 1) * 64;       // y-base
    const int lrow = lane & 15, lk = lane >> 4;
    const unsigned short* TRb = TR + (size_t)img * HW;
    const unsigned short* TIb = TI + (size_t)img * HW;

    f4v aR[4][4], aI[4][4];
#pragma unroll
    for (int m = 0; m < 4; m++)
#pragma unroll
        for (int n = 0; n < 4; n++) { aR[m][n] = (f4v){0,0,0,0}; aI[m][n] = (f4v){0,0,0,0}; }

#pragma unroll 1
    for (int k0 = 0; k0 < 256; k0 += 32) {
        bf8v afR[4], afI[4];
#pragma unroll
        for (int m = 0; m < 4; m++) {
            const int ro = (M0 + m * 16 + lrow) * 256 + k0 + lk * 8;
            afR[m] = *(const bf8v*)(TRb + ro);
            afI[m] = *(const bf8v*)(TIb + ro);
        }
#pragma unroll
        for (int n = 0; n < 4; n++) {
            const int ycol = N0 + n * 16 + lrow;
            const bf8v br = *(const bf8v*)(KBr + ycol * 256 + k0 + lk * 8);
            const bf8v bi = *(const bf8v*)(KBi + ycol * 256 + k0 + lk * 8);
#pragma unroll
            for (int m = 0; m < 4; m++) {
                aR[m][n] = __builtin_amdgcn_mfma_f32_16x16x32_bf16(afR[m], br, aR[m][n], 0, 0, 0);
                aI[m][n] = __builtin_amdgcn_mfma_f32_16x16x32_bf16(afI[m], bi, aI[m][n], 0, 0, 0);
            }
        }
    }
    // D[m=x][n=y]: lane col y = N0+n*16+lrow, rows x = M0+m*16+lk*4+0..3 -> low[y][x] float4
#pragma unroll
    for (int n = 0; n < 4; n++) {
        const size_t yoff = (size_t)img * HW + (size_t)(N0 + n * 16 + lrow) * 256;
#pragma unroll
        for (int m = 0; m < 4; m++) {
            const f4v r = aR[m][n], ii = aI[m][n];
            const float4 v = make_float4(r[0] - ii[0], r[1] - ii[1], r[2] - ii[2], r[3] - ii[3]);
            *(float4*)(low + yoff + M0 + m * 16 + lk * 4) = v;
        }
    }
}

// ---- W_eff = collapse(grouped 3x3, 1x1) -> bf16 [chunk][pos][oc][ch] ----
__global__ __launch_bounds__(256) void k_weff_bf(const float* __restrict__ w_u1,
    const float* __restrict__ w_con, unsigned short* __restrict__ wbf)
{
    const int f = blockIdx.x * 256 + threadIdx.x;   // 64*128*9 = 73728
    if (f >= 73728) return;
    const int ch = f & 31, oc = (f >> 5) & 63, cp = f >> 11;
    const int pos = cp % 9, cb = cp / 9;
    const int g = cb * 32 + ch;
    float s = 0.f;
#pragma unroll
    for (int j = 0; j < 4; j++) s += w_u1[oc * 512 + g * 4 + j] * w_con[(g * 4 + j) * 9 + pos];
    wbf[f] = bf16u(s);
}

// ---- fp32 OIHW 3x3 weights -> bf16 [chunk][pos][oc][ch] ----
template<int CIN>
__global__ __launch_bounds__(256) void k_wcvt(const float* __restrict__ w, unsigned short* __restrict__ wbf)
{
    const int f = blockIdx.x * 256 + threadIdx.x;   // 64*CIN*9
    if (f >= 64 * CIN * 9) return;
    const int ch = f & 31, oc = (f >> 5) & 63, cp = f >> 11;
    const int pos = cp % 9, cb = cp / 9;
    const int c = cb * 32 + ch;
    wbf[f] = bf16u(w[oc * CIN * 9 + c * 9 + pos]);
}

// ---------------- MFMA 3x3 conv: CIN -> 64 (bf16 in, fp32 acc) ----------------
template<int CIN>
__global__ __launch_bounds__(256, 2) void k_mconv(
    const float* __restrict__ in0, const float* __restrict__ in1,
    const unsigned short* __restrict__ wbf, const float* __restrict__ bias,
    float* __restrict__ out)
{
    __shared__ unsigned short Xl[4 * 260 * 32];
    const int tid = threadIdx.x;
    const int lane = tid & 63;
    const int wave = tid >> 6;
    const int b = blockIdx.x >> 7;
    const int y0 = (blockIdx.x & 127) * 2;
    const int row_sel = wave >> 1;          // which of the 2 output rows
    const int px_base = (wave & 1) * 128;   // px half

    for (int i = tid; i < 4 * 260 * 32 / 2; i += 256) ((unsigned int*)Xl)[i] = 0u;

    f4v acc[8][4];
#pragma unroll
    for (int i = 0; i < 8; i++)
#pragma unroll
        for (int n = 0; n < 4; n++) acc[i][n] = (f4v){0.f, 0.f, 0.f, 0.f};

    const int pxl   = px_base + (lane & 15);         // m-index base px
    const int gsl   = lane >> 4;                     // k-group (slot)
    const int wlane = (lane & 15) * 32 + gsl * 8;    // W-frag lane offset (ushorts)

    constexpr int NC = CIN / 32;
#pragma unroll 1
    for (int cb = 0; cb < NC; cb++) {
        const int c0 = cb * 32;
        const float* src = ((CIN == 128 && c0 >= 64) ? in1 : in0)
                           + ((size_t)b * 64 + (c0 & 63)) * HW;
        __syncthreads();
        {   // stage 4 rows x 32 ch x 256 px
            const int px = tid;
            const int px_idx = px + 1;
            const int sw = (px_idx >> 1) & 3;
#pragma unroll 1
            for (int r = 0; r < 4; r++) {
                const int yy = y0 - 1 + r;
                if (yy < 0 || yy > 255) continue;
                const float* rp = src + (size_t)yy * WIDTH + px;
#pragma unroll 4
                for (int d = 0; d < 16; d++) {
                    const float va = rp[(size_t)(2 * d) * HW];
                    const float vb = rp[(size_t)(2 * d + 1) * HW];
                    const unsigned int dw = (unsigned int)bf16u(va)
                                          | ((unsigned int)bf16u(vb) << 16);
                    const int byte = r * 16640 + px_idx * 64
                                   + (((d >> 2) ^ sw) << 4) + ((d & 3) << 2);
                    *(unsigned int*)((char*)Xl + byte) = dw;
                }
            }
        }
        __syncthreads();
#pragma unroll 1
        for (int pos = 0; pos < 9; pos++) {
            const int dy = pos / 3, dx = pos - dy * 3;
            const unsigned short* wp = wbf + (cb * 9 + pos) * 2048 + wlane;
            const bf8v wf0 = *(const bf8v*)(wp);
            const bf8v wf1 = *(const bf8v*)(wp + 512);
            const bf8v wf2 = *(const bf8v*)(wp + 1024);
            const bf8v wf3 = *(const bf8v*)(wp + 1536);
            const int pxe = pxl + dx;
            const int row = row_sel + dy;
            const char* abase = (const char*)Xl + row * 16640 + pxe * 64
                              + ((gsl ^ ((pxe >> 1) & 3)) << 4);
#pragma unroll
            for (int i = 0; i < 8; i++) {
                const bf8v af = *(const bf8v*)(abase + i * 1024);
                acc[i][0] = __builtin_amdgcn_mfma_f32_16x16x32_bf16(af, wf0, acc[i][0], 0, 0, 0);
                acc[i][1] = __builtin_amdgcn_mfma_f32_16x16x32_bf16(af, wf1, acc[i][1], 0, 0, 0);
                acc[i][2] = __builtin_amdgcn_mfma_f32_16x16x32_bf16(af, wf2, acc[i][2], 0, 0, 0);
                acc[i][3] = __builtin_amdgcn_mfma_f32_16x16x32_bf16(af, wf3, acc[i][3], 0, 0, 0);
            }
        }
    }
    const int yrow = y0 + row_sel;
#pragma unroll
    for (int n = 0; n < 4; n++) {
        const float bv = bias[n * 16 + (lane & 15)];
        float* po = out + ((size_t)(b * 64) + n * 16 + (lane & 15)) * HW
                  + (size_t)yrow * WIDTH + px_base + (lane >> 4) * 4;
#pragma unroll
        for (int i = 0; i < 8; i++) {
            const f4v a = acc[i][n];
            const float4 v = make_float4(a[0] + bv, a[1] + bv, a[2] + bv, a[3] + bv);
            *(float4*)(po + i * 16) = v;
        }
    }
}

// ---------------- generic fp32 conv (proj + 1x1s) ----------------
template<int CIN, int CHUNK, int KS, bool ADD>
__global__ __launch_bounds__(256, 3) void k_conv(const float* __restrict__ in0,
    const float* __restrict__ in1, const float* __restrict__ wt,
    const float* __restrict__ bias, const float* __restrict__ addsrc,
    float* __restrict__ out)
{
    __shared__ float wl[CHUNK][KS * KS][32];
    const int tid = threadIdx.x;
    const int og = tid >> 5, xg = tid & 31;
    const int half = blockIdx.x & 1;
    const int y = (blockIdx.x >> 1) & 255;
    const int b = blockIdx.x >> 9;
    const int o_base = half * 32;
    const int o0l = og * 4;
    const int x0 = xg * 8;
    constexpr int IC0 = (CIN == 128) ? 64 : CIN;

    float acc[4][8];
#pragma unroll
    for (int i = 0; i < 4; i++)
#pragma unroll
        for (int j = 0; j < 8; j++) acc[i][j] = 0.f;

    for (int c0 = 0; c0 < CIN; c0 += CHUNK) {
        __syncthreads();
        for (int idx = tid; idx < CHUNK * KS * KS * 32; idx += 256) {
            const int o = idx & 31;
            const int rest = idx >> 5;
            const int pos = rest % (KS * KS);
            const int cc = rest / (KS * KS);
            wl[cc][pos][o] = wt[((size_t)(o_base + o) * CIN + c0 + cc) * (KS * KS) + pos];
        }
        __syncthreads();
#pragma unroll 2
        for (int cc = 0; cc < CHUNK; cc++) {
            const int c = c0 + cc;
            const float* src = (CIN == 128 && c >= 64)
                ? (in1 + ((size_t)(b * 64 + (c - 64))) * HW)
                : (in0 + ((size_t)b * IC0 + c) * HW);
            if constexpr (KS == 3) {
#pragma unroll
                for (int dy = 0; dy < 3; dy++) {
                    const int yy = y + dy - 1;
                    float vv[10];
                    if (yy >= 0 && yy < 256) {
                        const float* r = src + (size_t)yy * WIDTH;
                        vv[0] = (x0 > 0) ? r[x0 - 1] : 0.f;
                        const float4 m0 = *(const float4*)(r + x0);
                        const float4 m1 = *(const float4*)(r + x0 + 4);
                        vv[1] = m0.x; vv[2] = m0.y; vv[3] = m0.z; vv[4] = m0.w;
                        vv[5] = m1.x; vv[6] = m1.y; vv[7] = m1.z; vv[8] = m1.w;
                        vv[9] = (x0 < 248) ? r[x0 + 8] : 0.f;
                    } else {
#pragma unroll
                        for (int q = 0; q < 10; q++) vv[q] = 0.f;
                    }
#pragma unroll
                    for (int dx = 0; dx < 3; dx++) {
                        const float4 w4 = *(const float4*)&wl[cc][dy * 3 + dx][o0l];
                        const float wv[4] = { w4.x, w4.y, w4.z, w4.w };
#pragma unroll
                        for (int oi = 0; oi < 4; oi++)
#pragma unroll
                            for (int px = 0; px < 8; px++)
                                acc[oi][px] += wv[oi] * vv[px + dx];
                    }
                }
            } else {
                const float4 m0 = *(const float4*)(src + (size_t)y * WIDTH + x0);
                const float4 m1 = *(const float4*)(src + (size_t)y * WIDTH + x0 + 4);
                const float vv[8] = { m0.x, m0.y, m0.z, m0.w, m1.x, m1.y, m1.z, m1.w };
                const float4 w4 = *(const float4*)&wl[cc][0][o0l];
                const float wv[4] = { w4.x, w4.y, w4.z, w4.w };
#pragma unroll
                for (int oi = 0; oi < 4; oi++)
#pragma unroll
                    for (int px = 0; px < 8; px++)
                        acc[oi][px] += wv[oi] * vv[px];
            }
        }
    }
#pragma unroll
    for (int oi = 0; oi < 4; oi++) {
        const int o = o_base + o0l + oi;
        const float bv = bias[o];
        const size_t off = ((size_t)(b * 64 + o)) * HW + (size_t)y * WIDTH + x0;
        float4 r0, r1;
        r0.x = acc[oi][0] + bv; r0.y = acc[oi][1] + bv; r0.z = acc[oi][2] + bv; r0.w = acc[oi][3] + bv;
        r1.x = acc[oi][4] + bv; r1.y = acc[oi][5] + bv; r1.z = acc[oi][6] + bv; r1.w = acc[oi][7] + bv;
        if constexpr (ADD) {
            const float4 a0 = *(const float4*)(addsrc + off);
            const float4 a1 = *(const float4*)(addsrc + off + 4);
            r0.x += a0.x; r0.y += a0.y; r0.z += a0.z; r0.w += a0.w;
            r1.x += a1.x; r1.y += a1.y; r1.z += a1.z; r1.w += a1.w;
        }
        *(float4*)(out + off) = r0;
        *(float4*)(out + off + 4) = r1;
    }
}

// ---------------- 2x2 max pool ----------------
__global__ __launch_bounds__(256) void k_maxpool(const float* __restrict__ feat, float* __restrict__ out)
{
    const int idx = blockIdx.x * 256 + threadIdx.x;
    const int xo = idx & 127;
    const int yo = (idx >> 7) & 127;
    const int img = idx >> 14;
    const float* p = feat + (size_t)img * HW + (size_t)(yo * 2) * WIDTH + xo * 2;
    out[idx] = fmaxf(fmaxf(p[0], p[1]), fmaxf(p[WIDTH], p[WIDTH + 1]));
}

extern "C" void kernel_launch(void* const* d_in, const int* in_sizes, int n_in,
                              void* d_out, int out_size, void* d_ws, size_t ws_size,
                              hipStream_t stream)
{
    const float* x      = (const float*)d_in[0];
    const float* w_proj = (const float*)d_in[1];
    const float* b_proj = (const float*)d_in[2];
    const float* w_a1   = (const float*)d_in[3];
    const float* w_a2   = (const float*)d_in[4];
    const float* w_ref  = (const float*)d_in[5];
    const float* b_ref  = (const float*)d_in[6];
    const float* w_fuse = (const float*)d_in[7];
    const float* b_fuse = (const float*)d_in[8];
    const float* w_con  = (const float*)d_in[9];
    const float* w_u1   = (const float*)d_in[10];
    const float* b_u1   = (const float*)d_in[11];
    const float* w_u2   = (const float*)d_in[12];
    const float* b_u2   = (const float*)d_in[13];
    const float* w_sc   = (const float*)d_in[14];
    const float* b_sc   = (const float*)d_in[15];

    float* wsf  = (float*)d_ws;
    float* buf0 = wsf;                       // xp -> low_f
    float* buf1 = wsf + (size_t)IMG;         // xw (normalized in place)
    float* buf2 = wsf + (size_t)2 * IMG;     // T1R/T1I bf16 overlay -> u2raw/u_b
    float* aux  = wsf + (size_t)3 * IMG;
    float* st0  = aux;
    float* st1  = aux + 512;
    float* st2  = aux + 1024;
    float* st3  = aux + 1536;
    float* st4  = aux + 2048;
    float* a2b  = aux + 2560;                // 256
    float* kr2  = aux + 2816;                // 512
    float* ki2  = aux + 3328;                // 512
    unsigned short* wbfA = (unsigned short*)(aux + 3840);    // 73728 ushort
    unsigned short* wbfB = wbfA + 73728;                     // 36864 ushort
    unsigned short* KBr  = wbfB + 36864;                     // 65536 ushort
    unsigned short* KBi  = KBr + 65536;                      // 65536 ushort

    float* fout = (float*)d_out;             // xpb(bf16) -> low -> u1raw/u_a -> feat
    float* pout = fout + (size_t)IMG;        // pooled
    unsigned short* xpb = (unsigned short*)fout;
    unsigned short* T1R = (unsigned short*)buf2;
    unsigned short* T1I = T1R + (size_t)IMG;

    k_tables<<<2, 256, 0, stream>>>(kr2, ki2);
    k_kmat<<<256, 256, 0, stream>>>(kr2, ki2, KBr, KBi);
    k_weff_bf<<<288, 256, 0, stream>>>(w_u1, w_con, wbfA);
    k_wcvt<64><<<144, 256, 0, stream>>>(w_u2, wbfB);
    k_conv<3, 3, 3, false><<<2048, 256, 0, stream>>>(x, nullptr, w_proj, b_proj, nullptr, buf0);
    k_stats<<<NIMG, 256, 0, stream>>>(buf0, st0);
    k_attention<<<1, 256, 0, stream>>>(st0, w_a1, w_a2, a2b);
    k_dw<<<65536, 256, 0, stream>>>(buf0, a2b, w_ref, b_ref, buf1);
    k_stats<<<NIMG, 256, 0, stream>>>(buf1, st1);
    k_norm<<<16384, 256, 0, stream>>>(buf1, st1);
    k_tobf<<<8192, 256, 0, stream>>>(buf0, xpb);
    k_mdft1<<<1024, 256, 0, stream>>>(xpb, KBr, KBi, T1R, T1I);
    k_mdft2<<<1024, 256, 0, stream>>>(T1R, T1I, KBr, KBi, fout);
    k_conv<64, 8, 1, false><<<2048, 256, 0, stream>>>(fout, nullptr, w_fuse, b_fuse, nullptr, buf0);
    k_stats<<<NIMG, 256, 0, stream>>>(buf0, st2);
    k_norm<<<16384, 256, 0, stream>>>(buf0, st2);
    k_mconv<128><<<512, 256, 0, stream>>>(buf1, buf0, wbfA, b_u1, fout);
    k_stats<<<NIMG, 256, 0, stream>>>(fout, st3);
    k_norm<<<16384, 256, 0, stream>>>(fout, st3);
    k_mconv<64><<<512, 256, 0, stream>>>(fout, nullptr, wbfB, b_u2, buf2);
    k_stats<<<NIMG, 256, 0, stream>>>(buf2, st4);
    k_norm<<<16384, 256, 0, stream>>>(buf2, st4);
    k_conv<128, 8, 1, true><<<2048, 256, 0, stream>>>(buf1, buf0, w_sc, b_sc, buf2, fout);
    k_maxpool<<<16384, 256, 0, stream>>>(fout, pout);
}

// Round 6
// 650.786 us; speedup vs baseline: 20.6927x; 1.2235x over previous
//
#include <hip/hip_runtime.h>
#include <hip/hip_bf16.h>

#define WIDTH 256
#define HW 65536
#define IMG 16777216   // 4*64*HW
#define NIMG 256

typedef __attribute__((ext_vector_type(8))) short bf8v;   // 8 bf16 = 4 VGPR (MFMA A/B frag)
typedef __attribute__((ext_vector_type(4))) float f4v;    // 4 f32 (MFMA C/D frag)

__device__ __forceinline__ float lrelu_f(float v){ return v > 0.f ? v : 0.01f*v; }
__device__ __forceinline__ unsigned short bf16u(float v){
    __hip_bfloat16 h = __float2bfloat16(v);
    return *(unsigned short*)&h;
}

// ---------------- stats stage 1: per-(image, 1/8th) partial sums ----------------
__global__ __launch_bounds__(256) void k_statsp(const float* __restrict__ src, float* __restrict__ ps)
{
    const int img = blockIdx.x >> 3, part = blockIdx.x & 7;
    const float4* p = (const float4*)(src + (size_t)img * HW) + part * 2048;
    float s = 0.f, s2 = 0.f;
    for (int i = threadIdx.x; i < 2048; i += 256) {
        const float4 v = p[i];
        s  += v.x + v.y + v.z + v.w;
        s2 += v.x * v.x + v.y * v.y + v.z * v.z + v.w * v.w;
    }
#pragma unroll
    for (int off = 32; off > 0; off >>= 1) {
        s  += __shfl_down(s, off, 64);
        s2 += __shfl_down(s2, off, 64);
    }
    __shared__ float ls[4], ls2[4];
    const int wid = threadIdx.x >> 6, lane = threadIdx.x & 63;
    if (lane == 0) { ls[wid] = s; ls2[wid] = s2; }
    __syncthreads();
    if (threadIdx.x == 0) {
        float S = 0.f, S2 = 0.f;
#pragma unroll
        for (int w = 0; w < 4; w++) { S += ls[w]; S2 += ls2[w]; }
        ps[blockIdx.x * 2]     = S;
        ps[blockIdx.x * 2 + 1] = S2;
    }
}

// ---------------- stats stage 2: finalize mean + inv_std (1 block) ----------------
__global__ __launch_bounds__(256) void k_statsf(const float* __restrict__ ps, float* __restrict__ st)
{
    const int img = threadIdx.x;
    float S = 0.f, S2 = 0.f;
#pragma unroll
    for (int q = 0; q < 8; q++) {
        S  += ps[(img * 8 + q) * 2];
        S2 += ps[(img * 8 + q) * 2 + 1];
    }
    const float m = S / 65536.f;
    const float var = S2 / 65536.f - m * m;
    st[img * 2]     = m;
    st[img * 2 + 1] = rsqrtf(var + 1e-5f);
}

// ---------------- attention MLP (single block) ----------------
__global__ __launch_bounds__(256) void k_attention(const float* __restrict__ st0,
    const float* __restrict__ wa1, const float* __restrict__ wa2, float* __restrict__ a2o)
{
    __shared__ float a1s[64];
    const int tid = threadIdx.x;
    if (tid < 64) {
        const int b = tid >> 4, o = tid & 15;
        float s = 0.f;
        for (int c = 0; c < 64; c++) s += wa1[o * 64 + c] * st0[(b * 64 + c) * 2];
        a1s[b * 16 + o] = lrelu_f(s);
    }
    __syncthreads();
    {
        const int b = tid >> 6, c = tid & 63;
        float s = 0.f;
#pragma unroll
        for (int o = 0; o < 16; o++) s += wa2[c * 16 + o] * a1s[b * 16 + o];
        a2o[tid] = 1.f / (1.f + expf(-s));
    }
}

// ---------------- depthwise 3x3 with folded attention scale (4 px/thread) ----------------
__global__ __launch_bounds__(256) void k_dw(const float* __restrict__ xp, const float* __restrict__ a2,
    const float* __restrict__ wref, const float* __restrict__ bref, float* __restrict__ out)
{
    const int tid = threadIdx.x;
    const int img = blockIdx.x >> 6;                       // 256 images x 64 row-groups
    const int y = ((blockIdx.x & 63) << 2) + (tid >> 6);   // 4 rows per block
    const int x0 = (tid & 63) * 4;
    const int c = img & 63;
    const float* src = xp + (size_t)img * HW;
    float wv[9];
#pragma unroll
    for (int k = 0; k < 9; k++) wv[k] = wref[c * 9 + k];
    const float scale = a2[img], bb = bref[c];

    float a[4] = {0.f, 0.f, 0.f, 0.f};
#pragma unroll
    for (int dy = 0; dy < 3; dy++) {
        const int yy = y + dy - 1;
        if (yy < 0 || yy > 255) continue;
        const float* r = src + (size_t)yy * WIDTH;
        float vv[6];
        vv[0] = (x0 > 0) ? r[x0 - 1] : 0.f;
        const float4 m = *(const float4*)(r + x0);
        vv[1] = m.x; vv[2] = m.y; vv[3] = m.z; vv[4] = m.w;
        vv[5] = (x0 < 252) ? r[x0 + 4] : 0.f;
#pragma unroll
        for (int dx = 0; dx < 3; dx++)
#pragma unroll
            for (int px = 0; px < 4; px++)
                a[px] += wv[dy * 3 + dx] * vv[px + dx];
    }
    float4 o;
    o.x = bb + scale * a[0]; o.y = bb + scale * a[1];
    o.z = bb + scale * a[2]; o.w = bb + scale * a[3];
    *(float4*)(out + (size_t)img * HW + (size_t)y * WIDTH + x0) = o;
}

// ---------------- in-place instance-norm + leaky relu ----------------
__global__ __launch_bounds__(256) void k_norm(float* __restrict__ buf, const float* __restrict__ st)
{
    const size_t i = (size_t)blockIdx.x * 256 + threadIdx.x;   // float4 index
    const int img = (int)(i >> 14);                            // 16384 float4 per image
    const float m = st[img * 2], s = st[img * 2 + 1];
    float4 v = ((float4*)buf)[i];
    v.x = lrelu_f((v.x - m) * s);
    v.y = lrelu_f((v.y - m) * s);
    v.z = lrelu_f((v.z - m) * s);
    v.w = lrelu_f((v.w - m) * s);
    ((float4*)buf)[i] = v;
}

// ---------------- Dirichlet kernel tables ----------------
__global__ void k_tables(float* __restrict__ kr2, float* __restrict__ ki2)
{
    const int t = blockIdx.x * 256 + threadIdx.x;
    if (t < 512) {
        const int tm = t & 255;
        const double PI = 3.14159265358979323846;
        const double th = 2.0 * PI * (double)tm / 256.0;
        double sr = 1.0;
        for (int k = 1; k <= 37; k++) sr += 2.0 * cos((double)k * th);
        sr += cos(38.0 * th);
        kr2[t] = (float)(sr / 256.0);
        ki2[t] = (float)(-sin(38.0 * th) / 256.0);
    }
}

// ---- circulant DFT matrices in MFMA-B-frag-friendly layout: KB[n][k] = f(n-k) ----
__global__ __launch_bounds__(256) void k_kmat(const float* __restrict__ kr2, const float* __restrict__ ki2,
    unsigned short* __restrict__ KBr, unsigned short* __restrict__ KBi)
{
    const int n = blockIdx.x, k = threadIdx.x;
    const int d = (n - k) & 255;
    KBr[n * 256 + k] = bf16u(kr2[d]);
    KBi[n * 256 + k] = bf16u(ki2[d]);
}

// ---------------- MFMA DFT pass 1 (x-direction), fp32 input with inline bf16 cvt ----------------
// T1{R,I}[x][y] = sum_xq xp[y][xq] * k{r,i}(x-xq); D stored transposed -> contiguous ushort4.
__global__ __launch_bounds__(256, 2) void k_mdft1(const float* __restrict__ xp,
    const unsigned short* __restrict__ KBr, const unsigned short* __restrict__ KBi,
    unsigned short* __restrict__ TR, unsigned short* __restrict__ TI)
{
    const int tid = threadIdx.x, lane = tid & 63, wave = tid >> 6;
    const int img = blockIdx.x >> 2;
    const int mb = (blockIdx.x >> 1) & 1, nb = blockIdx.x & 1;
    const int M0 = mb * 128 + (wave >> 1) * 64;      // y-base
    const int N0 = nb * 128 + (wave & 1) * 64;       // x-base
    const int lrow = lane & 15, lk = lane >> 4;
    const float* Xb = xp + (size_t)img * HW;

    f4v aR[4][4], aI[4][4];
#pragma unroll
    for (int m = 0; m < 4; m++)
#pragma unroll
        for (int n = 0; n < 4; n++) { aR[m][n] = (f4v){0,0,0,0}; aI[m][n] = (f4v){0,0,0,0}; }

#pragma unroll 1
    for (int k0 = 0; k0 < 256; k0 += 32) {
        bf8v af[4];
#pragma unroll
        for (int m = 0; m < 4; m++) {
            const float* rp = Xb + (size_t)(M0 + m * 16 + lrow) * 256 + k0 + lk * 8;
            const float4 a0 = *(const float4*)rp;
            const float4 a1 = *(const float4*)(rp + 4);
            bf8v t;
            t[0] = (short)bf16u(a0.x); t[1] = (short)bf16u(a0.y);
            t[2] = (short)bf16u(a0.z); t[3] = (short)bf16u(a0.w);
            t[4] = (short)bf16u(a1.x); t[5] = (short)bf16u(a1.y);
            t[6] = (short)bf16u(a1.z); t[7] = (short)bf16u(a1.w);
            af[m] = t;
        }
#pragma unroll
        for (int n = 0; n < 4; n++) {
            const int xcol = N0 + n * 16 + lrow;
            const bf8v br = *(const bf8v*)(KBr + xcol * 256 + k0 + lk * 8);
            const bf8v bi = *(const bf8v*)(KBi + xcol * 256 + k0 + lk * 8);
#pragma unroll
            for (int m = 0; m < 4; m++) {
                aR[m][n] = __builtin_amdgcn_mfma_f32_16x16x32_bf16(af[m], br, aR[m][n], 0, 0, 0);
                aI[m][n] = __builtin_amdgcn_mfma_f32_16x16x32_bf16(af[m], bi, aI[m][n], 0, 0, 0);
            }
        }
    }
#pragma unroll
    for (int n = 0; n < 4; n++) {
        const size_t xoff = (size_t)img * HW + (size_t)(N0 + n * 16 + lrow) * 256;
#pragma unroll
        for (int m = 0; m < 4; m++) {
            const size_t off = xoff + M0 + m * 16 + lk * 4;
            const f4v r = aR[m][n], ii = aI[m][n];
            ushort4 ur, ui;
            ur.x = bf16u(r[0]); ur.y = bf16u(r[1]); ur.z = bf16u(r[2]); ur.w = bf16u(r[3]);
            ui.x = bf16u(ii[0]); ui.y = bf16u(ii[1]); ui.z = bf16u(ii[2]); ui.w = bf16u(ii[3]);
            *(ushort4*)(TR + off) = ur;
            *(ushort4*)(TI + off) = ui;
        }
    }
}

// ---------------- MFMA DFT pass 2 (y-direction) ----------------
__global__ __launch_bounds__(256, 2) void k_mdft2(const unsigned short* __restrict__ TR,
    const unsigned short* __restrict__ TI, const unsigned short* __restrict__ KBr,
    const unsigned short* __restrict__ KBi, float* __restrict__ low)
{
    const int tid = threadIdx.x, lane = tid & 63, wave = tid >> 6;
    const int img = blockIdx.x >> 2;
    const int mb = (blockIdx.x >> 1) & 1, nb = blockIdx.x & 1;
    const int M0 = mb * 128 + (wave >> 1) * 64;      // x-base (rows of T1)
    const int N0 = nb * 128 + (wave & 1) * 64;       // y-base
    const int lrow = lane & 15, lk = lane >> 4;
    const unsigned short* TRb = TR + (size_t)img * HW;
    const unsigned short* TIb = TI + (size_t)img * HW;

    f4v aR[4][4], aI[4][4];
#pragma unroll
    for (int m = 0; m < 4; m++)
#pragma unroll
        for (int n = 0; n < 4; n++) { aR[m][n] = (f4v){0,0,0,0}; aI[m][n] = (f4v){0,0,0,0}; }

#pragma unroll 1
    for (int k0 = 0; k0 < 256; k0 += 32) {
        bf8v afR[4], afI[4];
#pragma unroll
        for (int m = 0; m < 4; m++) {
            const int ro = (M0 + m * 16 + lrow) * 256 + k0 + lk * 8;
            afR[m] = *(const bf8v*)(TRb + ro);
            afI[m] = *(const bf8v*)(TIb + ro);
        }
#pragma unroll
        for (int n = 0; n < 4; n++) {
            const int ycol = N0 + n * 16 + lrow;
            const bf8v br = *(const bf8v*)(KBr + ycol * 256 + k0 + lk * 8);
            const bf8v bi = *(const bf8v*)(KBi + ycol * 256 + k0 + lk * 8);
#pragma unroll
            for (int m = 0; m < 4; m++) {
                aR[m][n] = __builtin_amdgcn_mfma_f32_16x16x32_bf16(afR[m], br, aR[m][n], 0, 0, 0);
                aI[m][n] = __builtin_amdgcn_mfma_f32_16x16x32_bf16(afI[m], bi, aI[m][n], 0, 0, 0);
            }
        }
    }
#pragma unroll
    for (int n = 0; n < 4; n++) {
        const size_t yoff = (size_t)img * HW + (size_t)(N0 + n * 16 + lrow) * 256;
#pragma unroll
        for (int m = 0; m < 4; m++) {
            const f4v r = aR[m][n], ii = aI[m][n];
            const float4 v = make_float4(r[0] - ii[0], r[1] - ii[1], r[2] - ii[2], r[3] - ii[3]);
            *(float4*)(low + yoff + M0 + m * 16 + lk * 4) = v;
        }
    }
}

// ---- W_eff = collapse(grouped 3x3, 1x1) -> bf16 [chunk][pos][oc][ch] ----
__global__ __launch_bounds__(256) void k_weff_bf(const float* __restrict__ w_u1,
    const float* __restrict__ w_con, unsigned short* __restrict__ wbf)
{
    const int f = blockIdx.x * 256 + threadIdx.x;   // 64*128*9 = 73728
    if (f >= 73728) return;
    const int ch = f & 31, oc = (f >> 5) & 63, cp = f >> 11;
    const int pos = cp % 9, cb = cp / 9;
    const int g = cb * 32 + ch;
    float s = 0.f;
#pragma unroll
    for (int j = 0; j < 4; j++) s += w_u1[oc * 512 + g * 4 + j] * w_con[(g * 4 + j) * 9 + pos];
    wbf[f] = bf16u(s);
}

// ---- fp32 OIHW 3x3 weights -> bf16 [chunk][pos][oc][ch] ----
template<int CIN>
__global__ __launch_bounds__(256) void k_wcvt(const float* __restrict__ w, unsigned short* __restrict__ wbf)
{
    const int f = blockIdx.x * 256 + threadIdx.x;   // 64*CIN*9
    if (f >= 64 * CIN * 9) return;
    const int ch = f & 31, oc = (f >> 5) & 63, cp = f >> 11;
    const int pos = cp % 9, cb = cp / 9;
    const int c = cb * 32 + ch;
    wbf[f] = bf16u(w[oc * CIN * 9 + c * 9 + pos]);
}

// ---------------- MFMA 3x3 conv: CIN -> 64 (bf16 in, fp32 acc) ----------------
template<int CIN>
__global__ __launch_bounds__(256, 2) void k_mconv(
    const float* __restrict__ in0, const float* __restrict__ in1,
    const unsigned short* __restrict__ wbf, const float* __restrict__ bias,
    float* __restrict__ out)
{
    __shared__ unsigned short Xl[4 * 260 * 32];
    const int tid = threadIdx.x;
    const int lane = tid & 63;
    const int wave = tid >> 6;
    const int b = blockIdx.x >> 7;
    const int y0 = (blockIdx.x & 127) * 2;
    const int row_sel = wave >> 1;          // which of the 2 output rows
    const int px_base = (wave & 1) * 128;   // px half

    for (int i = tid; i < 4 * 260 * 32 / 2; i += 256) ((unsigned int*)Xl)[i] = 0u;

    f4v acc[8][4];
#pragma unroll
    for (int i = 0; i < 8; i++)
#pragma unroll
        for (int n = 0; n < 4; n++) acc[i][n] = (f4v){0.f, 0.f, 0.f, 0.f};

    const int pxl   = px_base + (lane & 15);         // m-index base px
    const int gsl   = lane >> 4;                     // k-group (slot)
    const int wlane = (lane & 15) * 32 + gsl * 8;    // W-frag lane offset (ushorts)

    constexpr int NC = CIN / 32;
#pragma unroll 1
    for (int cb = 0; cb < NC; cb++) {
        const int c0 = cb * 32;
        const float* src = ((CIN == 128 && c0 >= 64) ? in1 : in0)
                           + ((size_t)b * 64 + (c0 & 63)) * HW;
        __syncthreads();
        {   // stage 4 rows x 32 ch x 256 px
            const int px = tid;
            const int px_idx = px + 1;
            const int sw = (px_idx >> 1) & 3;
#pragma unroll 1
            for (int r = 0; r < 4; r++) {
                const int yy = y0 - 1 + r;
                if (yy < 0 || yy > 255) continue;
                const float* rp = src + (size_t)yy * WIDTH + px;
#pragma unroll 4
                for (int d = 0; d < 16; d++) {
                    const float va = rp[(size_t)(2 * d) * HW];
                    const float vb = rp[(size_t)(2 * d + 1) * HW];
                    const unsigned int dw = (unsigned int)bf16u(va)
                                          | ((unsigned int)bf16u(vb) << 16);
                    const int byte = r * 16640 + px_idx * 64
                                   + (((d >> 2) ^ sw) << 4) + ((d & 3) << 2);
                    *(unsigned int*)((char*)Xl + byte) = dw;
                }
            }
        }
        __syncthreads();
#pragma unroll 1
        for (int pos = 0; pos < 9; pos++) {
            const int dy = pos / 3, dx = pos - dy * 3;
            const unsigned short* wp = wbf + (cb * 9 + pos) * 2048 + wlane;
            const bf8v wf0 = *(const bf8v*)(wp);
            const bf8v wf1 = *(const bf8v*)(wp + 512);
            const bf8v wf2 = *(const bf8v*)(wp + 1024);
            const bf8v wf3 = *(const bf8v*)(wp + 1536);
            const int pxe = pxl + dx;
            const int row = row_sel + dy;
            const char* abase = (const char*)Xl + row * 16640 + pxe * 64
                              + ((gsl ^ ((pxe >> 1) & 3)) << 4);
#pragma unroll
            for (int i = 0; i < 8; i++) {
                const bf8v af = *(const bf8v*)(abase + i * 1024);
                acc[i][0] = __builtin_amdgcn_mfma_f32_16x16x32_bf16(af, wf0, acc[i][0], 0, 0, 0);
                acc[i][1] = __builtin_amdgcn_mfma_f32_16x16x32_bf16(af, wf1, acc[i][1], 0, 0, 0);
                acc[i][2] = __builtin_amdgcn_mfma_f32_16x16x32_bf16(af, wf2, acc[i][2], 0, 0, 0);
                acc[i][3] = __builtin_amdgcn_mfma_f32_16x16x32_bf16(af, wf3, acc[i][3], 0, 0, 0);
            }
        }
    }
    const int yrow = y0 + row_sel;
#pragma unroll
    for (int n = 0; n < 4; n++) {
        const float bv = bias[n * 16 + (lane & 15)];
        float* po = out + ((size_t)(b * 64) + n * 16 + (lane & 15)) * HW
                  + (size_t)yrow * WIDTH + px_base + (lane >> 4) * 4;
#pragma unroll
        for (int i = 0; i < 8; i++) {
            const f4v a = acc[i][n];
            const float4 v = make_float4(a[0] + bv, a[1] + bv, a[2] + bv, a[3] + bv);
            *(float4*)(po + i * 16) = v;
        }
    }
}

// ---------------- 1x1 conv: CIN -> 64, all weights in LDS, barrier-free K loop ----------------
// Block = one (b, y) row x all 64 oc; thread = 8 oc x 8 px (64 acc). One barrier total.
// R5 post-mortem: old k_conv<_,1> was latency-bound (16 barriers, VALUBusy 24%, HBM 22%).
template<int CIN, bool ADD>
__global__ __launch_bounds__(256, 4) void k_conv1(const float* __restrict__ in0,
    const float* __restrict__ in1, const float* __restrict__ wt,
    const float* __restrict__ bias, const float* __restrict__ addsrc,
    float* __restrict__ out)
{
    __shared__ float wl[CIN][64];
    const int tid = threadIdx.x;
    const int og = tid >> 5;           // 8 groups of 8 oc
    const int pg = tid & 31;           // 32 groups of 8 px
    const int y = blockIdx.x & 255;
    const int b = blockIdx.x >> 8;
    const int x0 = pg * 8;
    const int o0 = og * 8;

    for (int idx = tid; idx < CIN * 64; idx += 256) {
        const int o = idx & 63, c = idx >> 6;
        wl[c][o] = wt[o * CIN + c];
    }
    __syncthreads();

    float acc[8][8];
#pragma unroll
    for (int i = 0; i < 8; i++)
#pragma unroll
        for (int j = 0; j < 8; j++) acc[i][j] = 0.f;

    {
        const float* p = in0 + ((size_t)b * 64) * HW + (size_t)y * WIDTH + x0;
#pragma unroll 2
        for (int c = 0; c < 64; c++) {
            const float4 v0 = *(const float4*)(p + (size_t)c * HW);
            const float4 v1 = *(const float4*)(p + (size_t)c * HW + 4);
            const float4 wA = *(const float4*)&wl[c][o0];
            const float4 wB = *(const float4*)&wl[c][o0 + 4];
            const float wv[8] = { wA.x, wA.y, wA.z, wA.w, wB.x, wB.y, wB.z, wB.w };
            const float vv[8] = { v0.x, v0.y, v0.z, v0.w, v1.x, v1.y, v1.z, v1.w };
#pragma unroll
            for (int oi = 0; oi < 8; oi++)
#pragma unroll
                for (int px = 0; px < 8; px++)
                    acc[oi][px] += wv[oi] * vv[px];
        }
    }
    if constexpr (CIN == 128) {
        const float* p = in1 + ((size_t)b * 64) * HW + (size_t)y * WIDTH + x0;
#pragma unroll 2
        for (int c = 0; c < 64; c++) {
            const float4 v0 = *(const float4*)(p + (size_t)c * HW);
            const float4 v1 = *(const float4*)(p + (size_t)c * HW + 4);
            const float4 wA = *(const float4*)&wl[64 + c][o0];
            const float4 wB = *(const float4*)&wl[64 + c][o0 + 4];
            const float wv[8] = { wA.x, wA.y, wA.z, wA.w, wB.x, wB.y, wB.z, wB.w };
            const float vv[8] = { v0.x, v0.y, v0.z, v0.w, v1.x, v1.y, v1.z, v1.w };
#pragma unroll
            for (int oi = 0; oi < 8; oi++)
#pragma unroll
                for (int px = 0; px < 8; px++)
                    acc[oi][px] += wv[oi] * vv[px];
        }
    }

#pragma unroll
    for (int oi = 0; oi < 8; oi++) {
        const int o = o0 + oi;
        const float bv = bias[o];
        const size_t off = ((size_t)(b * 64 + o)) * HW + (size_t)y * WIDTH + x0;
        float4 r0, r1;
        r0.x = acc[oi][0] + bv; r0.y = acc[oi][1] + bv; r0.z = acc[oi][2] + bv; r0.w = acc[oi][3] + bv;
        r1.x = acc[oi][4] + bv; r1.y = acc[oi][5] + bv; r1.z = acc[oi][6] + bv; r1.w = acc[oi][7] + bv;
        if constexpr (ADD) {
            const float4 a0 = *(const float4*)(addsrc + off);
            const float4 a1 = *(const float4*)(addsrc + off + 4);
            r0.x += a0.x; r0.y += a0.y; r0.z += a0.z; r0.w += a0.w;
            r1.x += a1.x; r1.y += a1.y; r1.z += a1.z; r1.w += a1.w;
        }
        *(float4*)(out + off) = r0;
        *(float4*)(out + off + 4) = r1;
    }
}

// ---------------- generic fp32 conv (proj only) ----------------
template<int CIN, int CHUNK, int KS, bool ADD>
__global__ __launch_bounds__(256, 3) void k_conv(const float* __restrict__ in0,
    const float* __restrict__ in1, const float* __restrict__ wt,
    const float* __restrict__ bias, const float* __restrict__ addsrc,
    float* __restrict__ out)
{
    __shared__ float wl[CHUNK][KS * KS][32];
    const int tid = threadIdx.x;
    const int og = tid >> 5, xg = tid & 31;
    const int half = blockIdx.x & 1;
    const int y = (blockIdx.x >> 1) & 255;
    const int b = blockIdx.x >> 9;
    const int o_base = half * 32;
    const int o0l = og * 4;
    const int x0 = xg * 8;
    constexpr int IC0 = (CIN == 128) ? 64 : CIN;

    float acc[4][8];
#pragma unroll
    for (int i = 0; i < 4; i++)
#pragma unroll
        for (int j = 0; j < 8; j++) acc[i][j] = 0.f;

    for (int c0 = 0; c0 < CIN; c0 += CHUNK) {
        __syncthreads();
        for (int idx = tid; idx < CHUNK * KS * KS * 32; idx += 256) {
            const int o = idx & 31;
            const int rest = idx >> 5;
            const int pos = rest % (KS * KS);
            const int cc = rest / (KS * KS);
            wl[cc][pos][o] = wt[((size_t)(o_base + o) * CIN + c0 + cc) * (KS * KS) + pos];
        }
        __syncthreads();
#pragma unroll 2
        for (int cc = 0; cc < CHUNK; cc++) {
            const int c = c0 + cc;
            const float* src = (CIN == 128 && c >= 64)
                ? (in1 + ((size_t)(b * 64 + (c - 64))) * HW)
                : (in0 + ((size_t)b * IC0 + c) * HW);
            if constexpr (KS == 3) {
#pragma unroll
                for (int dy = 0; dy < 3; dy++) {
                    const int yy = y + dy - 1;
                    float vv[10];
                    if (yy >= 0 && yy < 256) {
                        const float* r = src + (size_t)yy * WIDTH;
                        vv[0] = (x0 > 0) ? r[x0 - 1] : 0.f;
                        const float4 m0 = *(const float4*)(r + x0);
                        const float4 m1 = *(const float4*)(r + x0 + 4);
                        vv[1] = m0.x; vv[2] = m0.y; vv[3] = m0.z; vv[4] = m0.w;
                        vv[5] = m1.x; vv[6] = m1.y; vv[7] = m1.z; vv[8] = m1.w;
                        vv[9] = (x0 < 248) ? r[x0 + 8] : 0.f;
                    } else {
#pragma unroll
                        for (int q = 0; q < 10; q++) vv[q] = 0.f;
                    }
#pragma unroll
                    for (int dx = 0; dx < 3; dx++) {
                        const float4 w4 = *(const float4*)&wl[cc][dy * 3 + dx][o0l];
                        const float wv[4] = { w4.x, w4.y, w4.z, w4.w };
#pragma unroll
                        for (int oi = 0; oi < 4; oi++)
#pragma unroll
                            for (int px = 0; px < 8; px++)
                                acc[oi][px] += wv[oi] * vv[px + dx];
                    }
                }
            } else {
                const float4 m0 = *(const float4*)(src + (size_t)y * WIDTH + x0);
                const float4 m1 = *(const float4*)(src + (size_t)y * WIDTH + x0 + 4);
                const float vv[8] = { m0.x, m0.y, m0.z, m0.w, m1.x, m1.y, m1.z, m1.w };
                const float4 w4 = *(const float4*)&wl[cc][0][o0l];
                const float wv[4] = { w4.x, w4.y, w4.z, w4.w };
#pragma unroll
                for (int oi = 0; oi < 4; oi++)
#pragma unroll
                    for (int px = 0; px < 8; px++)
                        acc[oi][px] += wv[oi] * vv[px];
            }
        }
    }
#pragma unroll
    for (int oi = 0; oi < 4; oi++) {
        const int o = o_base + o0l + oi;
        const float bv = bias[o];
        const size_t off = ((size_t)(b * 64 + o)) * HW + (size_t)y * WIDTH + x0;
        float4 r0, r1;
        r0.x = acc[oi][0] + bv; r0.y = acc[oi][1] + bv; r0.z = acc[oi][2] + bv; r0.w = acc[oi][3] + bv;
        r1.x = acc[oi][4] + bv; r1.y = acc[oi][5] + bv; r1.z = acc[oi][6] + bv; r1.w = acc[oi][7] + bv;
        if constexpr (ADD) {
            const float4 a0 = *(const float4*)(addsrc + off);
            const float4 a1 = *(const float4*)(addsrc + off + 4);
            r0.x += a0.x; r0.y += a0.y; r0.z += a0.z; r0.w += a0.w;
            r1.x += a1.x; r1.y += a1.y; r1.z += a1.z; r1.w += a1.w;
        }
        *(float4*)(out + off) = r0;
        *(float4*)(out + off + 4) = r1;
    }
}

// ---------------- 2x2 max pool ----------------
__global__ __launch_bounds__(256) void k_maxpool(const float* __restrict__ feat, float* __restrict__ out)
{
    const int idx = blockIdx.x * 256 + threadIdx.x;
    const int xo = idx & 127;
    const int yo = (idx >> 7) & 127;
    const int img = idx >> 14;
    const float* p = feat + (size_t)img * HW + (size_t)(yo * 2) * WIDTH + xo * 2;
    out[idx] = fmaxf(fmaxf(p[0], p[1]), fmaxf(p[WIDTH], p[WIDTH + 1]));
}

extern "C" void kernel_launch(void* const* d_in, const int* in_sizes, int n_in,
                              void* d_out, int out_size, void* d_ws, size_t ws_size,
                              hipStream_t stream)
{
    const float* x      = (const float*)d_in[0];
    const float* w_proj = (const float*)d_in[1];
    const float* b_proj = (const float*)d_in[2];
    const float* w_a1   = (const float*)d_in[3];
    const float* w_a2   = (const float*)d_in[4];
    const float* w_ref  = (const float*)d_in[5];
    const float* b_ref  = (const float*)d_in[6];
    const float* w_fuse = (const float*)d_in[7];
    const float* b_fuse = (const float*)d_in[8];
    const float* w_con  = (const float*)d_in[9];
    const float* w_u1   = (const float*)d_in[10];
    const float* b_u1   = (const float*)d_in[11];
    const float* w_u2   = (const float*)d_in[12];
    const float* b_u2   = (const float*)d_in[13];
    const float* w_sc   = (const float*)d_in[14];
    const float* b_sc   = (const float*)d_in[15];

    float* wsf  = (float*)d_ws;
    float* buf0 = wsf;                       // xp -> low_f
    float* buf1 = wsf + (size_t)IMG;         // xw (normalized in place)
    float* buf2 = wsf + (size_t)2 * IMG;     // T1R/T1I bf16 overlay -> u2raw/u_b
    float* aux  = wsf + (size_t)3 * IMG;
    float* st0  = aux;
    float* st1  = aux + 512;
    float* st2  = aux + 1024;
    float* st3  = aux + 1536;
    float* st4  = aux + 2048;
    float* a2b  = aux + 2560;                // 256
    float* kr2  = aux + 2816;                // 512
    float* ki2  = aux + 3328;                // 512
    unsigned short* wbfA = (unsigned short*)(aux + 3840);    // 73728 ushort
    unsigned short* wbfB = wbfA + 73728;                     // 36864 ushort
    unsigned short* KBr  = wbfB + 36864;                     // 65536 ushort
    unsigned short* KBi  = KBr + 65536;                      // 65536 ushort
    float* ps   = (float*)(KBi + 65536);                     // 4096 floats (stats partials)

    float* fout = (float*)d_out;             // low -> u1raw/u_a -> feat
    float* pout = fout + (size_t)IMG;        // pooled
    unsigned short* T1R = (unsigned short*)buf2;
    unsigned short* T1I = T1R + (size_t)IMG;

    k_tables<<<2, 256, 0, stream>>>(kr2, ki2);
    k_kmat<<<256, 256, 0, stream>>>(kr2, ki2, KBr, KBi);
    k_weff_bf<<<288, 256, 0, stream>>>(w_u1, w_con, wbfA);
    k_wcvt<64><<<144, 256, 0, stream>>>(w_u2, wbfB);
    k_conv<3, 3, 3, false><<<2048, 256, 0, stream>>>(x, nullptr, w_proj, b_proj, nullptr, buf0);
    k_statsp<<<2048, 256, 0, stream>>>(buf0, ps);
    k_statsf<<<1, 256, 0, stream>>>(ps, st0);
    k_attention<<<1, 256, 0, stream>>>(st0, w_a1, w_a2, a2b);
    k_dw<<<16384, 256, 0, stream>>>(buf0, a2b, w_ref, b_ref, buf1);
    k_statsp<<<2048, 256, 0, stream>>>(buf1, ps);
    k_statsf<<<1, 256, 0, stream>>>(ps, st1);
    k_norm<<<16384, 256, 0, stream>>>(buf1, st1);
    k_mdft1<<<1024, 256, 0, stream>>>(buf0, KBr, KBi, T1R, T1I);
    k_mdft2<<<1024, 256, 0, stream>>>(T1R, T1I, KBr, KBi, fout);
    k_conv1<64, false><<<1024, 256, 0, stream>>>(fout, nullptr, w_fuse, b_fuse, nullptr, buf0);
    k_statsp<<<2048, 256, 0, stream>>>(buf0, ps);
    k_statsf<<<1, 256, 0, stream>>>(ps, st2);
    k_norm<<<16384, 256, 0, stream>>>(buf0, st2);
    k_mconv<128><<<512, 256, 0, stream>>>(buf1, buf0, wbfA, b_u1, fout);
    k_statsp<<<2048, 256, 0, stream>>>(fout, ps);
    k_statsf<<<1, 256, 0, stream>>>(ps, st3);
    k_norm<<<16384, 256, 0, stream>>>(fout, st3);
    k_mconv<64><<<512, 256, 0, stream>>>(fout, nullptr, wbfB, b_u2, buf2);
    k_statsp<<<2048, 256, 0, stream>>>(buf2, ps);
    k_statsf<<<1, 256, 0, stream>>>(ps, st4);
    k_norm<<<16384, 256, 0, stream>>>(buf2, st4);
    k_conv1<128, true><<<1024, 256, 0, stream>>>(buf1, buf0, w_sc, b_sc, buf2, fout);
    k_maxpool<<<16384, 256, 0, stream>>>(fout, pout);
}